// Round 1
// baseline (2303.545 us; speedup 1.0000x reference)
//
#include <hip/hip_runtime.h>
#include <math.h>

#define N_NODES 50000
#define N_EDGES 800000
#define D_IN    128
#define H1_     256
#define H2_     128
#define NG      64
#define NC_     2
#define BN_EPS  1e-5f

// ---------------------------------------------------------------------------
// scatter-add aggregation: agg[dst] += x[src]; optional edge counts
// ---------------------------------------------------------------------------
template<int D, bool CNT>
__global__ void scatter_kernel(const float* __restrict__ x, const int* __restrict__ ei,
                               float* __restrict__ agg, float* __restrict__ cnt)
{
    long long gid = (long long)blockIdx.x * blockDim.x + threadIdx.x;
    if (gid >= (long long)N_EDGES * D) return;
    int e = (int)(gid >> (D == 128 ? 7 : 8));
    int d = (int)(gid & (D - 1));
    int s = ei[e];
    int t = ei[N_EDGES + e];
    atomicAdd(&agg[(size_t)t * D + d], x[(size_t)s * D + d]);
    if (CNT && d == 0) atomicAdd(&cnt[t], 1.0f);
}

// ---------------------------------------------------------------------------
// fused GEMM: t[n,j] = sum_k mean[n,k]*Wl[k,j] + x[n,k]*Wr[k,j] + bl[j]
//             r[n,j] = sum_k x[n,k]*Wp[k,j] + bp[j]
// mean[n,k] = agg[n,k] / max(cnt[n],1)
// block = HOUT threads (one column each), RB rows per block, operands in LDS
// ---------------------------------------------------------------------------
template<int K, int HOUT, int RB>
__global__ __launch_bounds__(HOUT) void gemm_fused(
    const float* __restrict__ aggr, const float* __restrict__ cnt,
    const float* __restrict__ xin,
    const float* __restrict__ Wl, const float* __restrict__ bl,
    const float* __restrict__ Wr,
    const float* __restrict__ Wp, const float* __restrict__ bp,
    float* __restrict__ tout, float* __restrict__ rout)
{
    __shared__ float ms[RB][K];
    __shared__ float xs[RB][K];
    int n0 = blockIdx.x * RB;
    int tid = threadIdx.x;
    for (int i = tid; i < RB * K; i += HOUT) {
        int r = i / K, k = i % K;
        int n = n0 + r;
        float xv = 0.f, mv = 0.f;
        if (n < N_NODES) {
            xv = xin[(size_t)n * K + k];
            float c = cnt[n];
            mv = aggr[(size_t)n * K + k] / fmaxf(c, 1.0f);
        }
        xs[r][k] = xv;
        ms[r][k] = mv;
    }
    __syncthreads();

    int j = tid;
    float acc_t[RB], acc_r[RB];
    float blj = bl[j], bpj = bp[j];
    #pragma unroll
    for (int r = 0; r < RB; ++r) { acc_t[r] = blj; acc_r[r] = bpj; }

    for (int k = 0; k < K; ++k) {
        float wl = Wl[k * HOUT + j];
        float wr = Wr[k * HOUT + j];
        float wp = Wp[k * HOUT + j];
        #pragma unroll
        for (int r = 0; r < RB; ++r) {
            acc_t[r] += ms[r][k] * wl + xs[r][k] * wr;
            acc_r[r] += xs[r][k] * wp;
        }
    }
    #pragma unroll
    for (int r = 0; r < RB; ++r) {
        int n = n0 + r;
        if (n < N_NODES) {
            tout[(size_t)n * HOUT + j] = acc_t[r];
            rout[(size_t)n * HOUT + j] = acc_r[r];
        }
    }
}

// ---------------------------------------------------------------------------
// per-row L2 normalize (in place) + accumulate column sum / sumsq for BN
// ---------------------------------------------------------------------------
template<int H>
__global__ __launch_bounds__(H) void rownorm_stats(
    float* __restrict__ t, float* __restrict__ colsum, float* __restrict__ colsumsq)
{
    __shared__ float part[H / 64];
    int j = threadIdx.x;
    int wave = j >> 6, lane = j & 63;
    float cs = 0.f, cq = 0.f;
    for (int n = blockIdx.x; n < N_NODES; n += gridDim.x) {
        float v = t[(size_t)n * H + j];
        float s = v * v;
        #pragma unroll
        for (int off = 32; off > 0; off >>= 1) s += __shfl_xor(s, off);
        if (lane == 0) part[wave] = s;
        __syncthreads();
        float tot = 0.f;
        #pragma unroll
        for (int w = 0; w < H / 64; ++w) tot += part[w];
        float inv = 1.0f / fmaxf(sqrtf(tot), 1e-12f);
        v *= inv;
        t[(size_t)n * H + j] = v;
        cs += v;
        cq += v * v;
        __syncthreads();
    }
    atomicAdd(&colsum[j], cs);
    atomicAdd(&colsumsq[j], cq);
}

// ---------------------------------------------------------------------------
// BN constants: scale = g*rsqrt(var+eps), shift = be - mu*scale
// ---------------------------------------------------------------------------
template<int H>
__global__ void bn_finalize(const float* __restrict__ colsum, const float* __restrict__ colsumsq,
                            const float* __restrict__ g, const float* __restrict__ be,
                            float* __restrict__ scale, float* __restrict__ shift)
{
    int j = threadIdx.x;
    if (j < H) {
        float mu = colsum[j] / (float)N_NODES;
        float var = colsumsq[j] / (float)N_NODES - mu * mu;
        float sc = g[j] * rsqrtf(var + BN_EPS);
        scale[j] = sc;
        shift[j] = be[j] - mu * sc;
    }
}

// ---------------------------------------------------------------------------
// layer 0 epilogue: h = relu(t*scale+shift) + r   (in place over t)
// ---------------------------------------------------------------------------
__global__ void ew0_kernel(float* __restrict__ t, const float* __restrict__ r,
                           const float* __restrict__ scale, const float* __restrict__ shift)
{
    long long gid = (long long)blockIdx.x * blockDim.x + threadIdx.x;
    if (gid >= (long long)N_NODES * H1_) return;
    int j = (int)(gid & (H1_ - 1));
    float v = t[gid] * scale[j] + shift[j];
    t[gid] = fmaxf(v, 0.f) + r[gid];
}

// ---------------------------------------------------------------------------
// layer 1 epilogue fused with mean-pool scatter (batch is sorted -> run-length
// accumulate in registers, flush one atomic per graph transition)
// ---------------------------------------------------------------------------
__global__ __launch_bounds__(H2_) void ew1_pool_kernel(
    const float* __restrict__ t, const float* __restrict__ r,
    const float* __restrict__ scale, const float* __restrict__ shift,
    const int* __restrict__ batch,
    float* __restrict__ pooled, float* __restrict__ pcnt)
{
    int j = threadIdx.x;                // 0..127 (column)
    int n0 = blockIdx.x * 64;
    int nend = min(n0 + 64, N_NODES);
    float acc = 0.f, cacc = 0.f;
    int run = -1;
    float sc = scale[j], sh = shift[j];
    for (int n = n0; n < nend; ++n) {
        int b = batch[n];
        if (b != run) {
            if (run >= 0) {
                atomicAdd(&pooled[run * H2_ + j], acc);
                if (j == 0) atomicAdd(&pcnt[run], cacc);
            }
            run = b; acc = 0.f; cacc = 0.f;
        }
        float v = t[(size_t)n * H2_ + j] * sc + sh;
        v = fmaxf(v, 0.f) + r[(size_t)n * H2_ + j];
        acc += v;
        cacc += 1.f;
    }
    if (run >= 0) {
        atomicAdd(&pooled[run * H2_ + j], acc);
        if (j == 0) atomicAdd(&pcnt[run], cacc);
    }
}

// ---------------------------------------------------------------------------
// emb = pooled / max(count,1); write to ws copy and to d_out tail
// ---------------------------------------------------------------------------
__global__ void pool_fin_kernel(const float* __restrict__ pooled, const float* __restrict__ pcnt,
                                float* __restrict__ emb, float* __restrict__ emb_out)
{
    int gid = blockIdx.x * blockDim.x + threadIdx.x;
    if (gid < NG * H2_) {
        int g = gid >> 7;
        float v = pooled[gid] / fmaxf(pcnt[g], 1.0f);
        emb[gid] = v;
        emb_out[gid] = v;
    }
}

// ---------------------------------------------------------------------------
// classifier: Linear(128,256)+BN+ReLU, Linear(256,128)+BN+ReLU, Linear(128,2)
// single block; one thread per output column -> BN over 64 rows is thread-local
// ---------------------------------------------------------------------------
__global__ __launch_bounds__(256) void classifier_kernel(
    const float* __restrict__ emb,
    const float* __restrict__ Wc0, const float* __restrict__ bc0,
    const float* __restrict__ gc0, const float* __restrict__ bec0,
    const float* __restrict__ Wc1, const float* __restrict__ bc1,
    const float* __restrict__ gc1, const float* __restrict__ bec1,
    const float* __restrict__ Wc2, const float* __restrict__ bc2,
    float* __restrict__ logits)
{
    __shared__ float es[NG][H2_];   // 32 KB: emb, later reused for z1
    __shared__ float z0[NG][256];   // 64 KB
    int tid = threadIdx.x;
    for (int i = tid; i < NG * H2_; i += 256) es[i >> 7][i & 127] = emb[i];
    __syncthreads();

    { // stage A: z0 = relu(bn(emb @ Wc0 + bc0))
        int j = tid;
        float acc[NG];
        float b = bc0[j];
        #pragma unroll
        for (int r2 = 0; r2 < NG; ++r2) acc[r2] = b;
        for (int k = 0; k < H2_; ++k) {
            float w = Wc0[k * 256 + j];
            #pragma unroll
            for (int r2 = 0; r2 < NG; ++r2) acc[r2] += es[r2][k] * w;
        }
        float mu = 0.f;
        #pragma unroll
        for (int r2 = 0; r2 < NG; ++r2) mu += acc[r2];
        mu *= (1.0f / NG);
        float var = 0.f;
        #pragma unroll
        for (int r2 = 0; r2 < NG; ++r2) { float d = acc[r2] - mu; var += d * d; }
        var *= (1.0f / NG);
        float sc = gc0[j] * rsqrtf(var + BN_EPS);
        float sh = bec0[j] - mu * sc;
        #pragma unroll
        for (int r2 = 0; r2 < NG; ++r2) z0[r2][j] = fmaxf(acc[r2] * sc + sh, 0.f);
    }
    __syncthreads();

    if (tid < H2_) { // stage B: z1 = relu(bn(z0 @ Wc1 + bc1)) -> es
        int j = tid;
        float acc[NG];
        float b = bc1[j];
        #pragma unroll
        for (int r2 = 0; r2 < NG; ++r2) acc[r2] = b;
        for (int k = 0; k < 256; ++k) {
            float w = Wc1[k * H2_ + j];
            #pragma unroll
            for (int r2 = 0; r2 < NG; ++r2) acc[r2] += z0[r2][k] * w;
        }
        float mu = 0.f;
        #pragma unroll
        for (int r2 = 0; r2 < NG; ++r2) mu += acc[r2];
        mu *= (1.0f / NG);
        float var = 0.f;
        #pragma unroll
        for (int r2 = 0; r2 < NG; ++r2) { float d = acc[r2] - mu; var += d * d; }
        var *= (1.0f / NG);
        float sc = gc1[j] * rsqrtf(var + BN_EPS);
        float sh = bec1[j] - mu * sc;
        #pragma unroll
        for (int r2 = 0; r2 < NG; ++r2) es[r2][j] = fmaxf(acc[r2] * sc + sh, 0.f);
    }
    __syncthreads();

    if (tid < NG * NC_) { // stage C: logits
        int r2 = tid >> 1, c = tid & 1;
        float acc = bc2[c];
        for (int k = 0; k < H2_; ++k) acc += es[r2][k] * Wc2[k * NC_ + c];
        logits[r2 * NC_ + c] = acc;
    }
}

// ---------------------------------------------------------------------------
extern "C" void kernel_launch(void* const* d_in, const int* in_sizes, int n_in,
                              void* d_out, int out_size, void* d_ws, size_t ws_size,
                              hipStream_t stream)
{
    const float* x    = (const float*)d_in[0];
    const int*   ei   = (const int*)d_in[1];
    const int*   batch= (const int*)d_in[2];
    const float* Wl0  = (const float*)d_in[3];
    const float* bl0  = (const float*)d_in[4];
    const float* Wr0  = (const float*)d_in[5];
    const float* g0   = (const float*)d_in[6];
    const float* be0  = (const float*)d_in[7];
    const float* Wl1  = (const float*)d_in[8];
    const float* bl1  = (const float*)d_in[9];
    const float* Wr1  = (const float*)d_in[10];
    const float* g1   = (const float*)d_in[11];
    const float* be1  = (const float*)d_in[12];
    const float* Wp0  = (const float*)d_in[13];
    const float* bp0  = (const float*)d_in[14];
    const float* Wp1  = (const float*)d_in[15];
    const float* bp1  = (const float*)d_in[16];
    const float* Wc0  = (const float*)d_in[17];
    const float* bc0  = (const float*)d_in[18];
    const float* gc0  = (const float*)d_in[19];
    const float* bec0 = (const float*)d_in[20];
    const float* Wc1  = (const float*)d_in[21];
    const float* bc1  = (const float*)d_in[22];
    const float* gc1  = (const float*)d_in[23];
    const float* bec1 = (const float*)d_in[24];
    const float* Wc2  = (const float*)d_in[25];
    const float* bc2  = (const float*)d_in[26];

    // workspace layout (floats); total = 38,468,096 floats = 146.8 MiB
    float* ws        = (float*)d_ws;
    float* cnt       = ws;                    // 50048
    float* colsum0   = ws + 50048;            // 256
    float* colsumsq0 = colsum0 + 256;         // 256
    float* colsum1   = colsumsq0 + 256;       // 128
    float* colsumsq1 = colsum1 + 128;         // 128
    float* ss0       = colsumsq1 + 128;       // 512 (scale0, shift0)
    float* ss1       = ss0 + 512;             // 256 (scale1, shift1)
    float* pooled    = ss1 + 256;             // 8192
    float* pcnt      = pooled + 8192;         // 64
    float* emb       = pcnt + 64;             // 8192
    float* A         = ws + 68096;            // 6.4M  : agg0 / t1
    float* B         = A + 6400000;           // 12.8M : t0 / h0
    float* C         = B + 12800000;          // 12.8M : r0 / agg1
    float* D         = C + 12800000;          // 6.4M  : r1

    float* logits_out = (float*)d_out;
    float* emb_out    = logits_out + NG * NC_;

    // zero stats block + agg0 in one contiguous memset
    hipMemsetAsync(d_ws, 0, (size_t)(68096 + 6400000) * sizeof(float), stream);

    // ---- layer 0 ----
    {
        long long tot = (long long)N_EDGES * D_IN;
        scatter_kernel<D_IN, true><<<(int)((tot + 255) / 256), 256, 0, stream>>>(x, ei, A, cnt);
    }
    gemm_fused<D_IN, H1_, 32><<<(N_NODES + 31) / 32, H1_, 0, stream>>>(
        A, cnt, x, Wl0, bl0, Wr0, Wp0, bp0, B, C);
    rownorm_stats<H1_><<<1024, H1_, 0, stream>>>(B, colsum0, colsumsq0);
    bn_finalize<H1_><<<1, H1_, 0, stream>>>(colsum0, colsumsq0, g0, be0, ss0, ss0 + 256);
    {
        long long tot = (long long)N_NODES * H1_;
        ew0_kernel<<<(int)((tot + 255) / 256), 256, 0, stream>>>(B, C, ss0, ss0 + 256);
    }

    // ---- layer 1 ----
    hipMemsetAsync(C, 0, (size_t)12800000 * sizeof(float), stream);  // agg1
    {
        long long tot = (long long)N_EDGES * H1_;
        scatter_kernel<H1_, false><<<(int)((tot + 255) / 256), 256, 0, stream>>>(B, ei, C, nullptr);
    }
    gemm_fused<H1_, H2_, 32><<<(N_NODES + 31) / 32, H2_, 0, stream>>>(
        C, cnt, B, Wl1, bl1, Wr1, Wp1, bp1, A, D);
    rownorm_stats<H2_><<<1024, H2_, 0, stream>>>(A, colsum1, colsumsq1);
    bn_finalize<H2_><<<1, H2_, 0, stream>>>(colsum1, colsumsq1, g1, be1, ss1, ss1 + 128);
    ew1_pool_kernel<<<(N_NODES + 63) / 64, H2_, 0, stream>>>(
        A, D, ss1, ss1 + 128, batch, pooled, pcnt);

    // ---- pooling + classifier ----
    pool_fin_kernel<<<32, 256, 0, stream>>>(pooled, pcnt, emb, emb_out);
    classifier_kernel<<<1, 256, 0, stream>>>(
        emb, Wc0, bc0, gc0, bec0, Wc1, bc1, gc1, bec1, Wc2, bc2, logits_out);
}

// Round 2
// 1617.060 us; speedup vs baseline: 1.4245x; 1.4245x over previous
//
#include <hip/hip_runtime.h>
#include <math.h>

#define N_NODES 50000
#define N_EDGES 800000
#define D_IN    128
#define H1_     256
#define H2_     128
#define NG      64
#define NC_     2
#define BN_EPS  1e-5f

// ---------------------------------------------------------------------------
// CSR build step 1: degree count per destination node
// ---------------------------------------------------------------------------
__global__ void degree_kernel(const int* __restrict__ ei, int* __restrict__ deg)
{
    int e = blockIdx.x * 256 + threadIdx.x;
    if (e < N_EDGES) atomicAdd(&deg[ei[N_EDGES + e]], 1);
}

// ---------------------------------------------------------------------------
// CSR build step 2: exclusive scan of degrees -> rowptr (and cursor copy)
// single block, chunked Hillis-Steele in LDS
// ---------------------------------------------------------------------------
__global__ __launch_bounds__(1024) void scan_kernel(const int* __restrict__ deg,
                                                    int* __restrict__ rowptr,
                                                    int* __restrict__ cursor)
{
    __shared__ int buf[1024];
    __shared__ int carry_s;
    if (threadIdx.x == 0) carry_s = 0;
    __syncthreads();
    for (int base = 0; base < N_NODES; base += 1024) {
        int i = base + threadIdx.x;
        int v = (i < N_NODES) ? deg[i] : 0;
        buf[threadIdx.x] = v;
        __syncthreads();
        for (int off = 1; off < 1024; off <<= 1) {
            int t = (threadIdx.x >= off) ? buf[threadIdx.x - off] : 0;
            __syncthreads();
            buf[threadIdx.x] += t;
            __syncthreads();
        }
        int carry = carry_s;
        int excl = carry + buf[threadIdx.x] - v;
        if (i < N_NODES) { rowptr[i] = excl; cursor[i] = excl; }
        if (i == N_NODES - 1) rowptr[N_NODES] = excl + v;
        __syncthreads();
        if (threadIdx.x == 1023) carry_s = carry + buf[1023];
        __syncthreads();
    }
}

// ---------------------------------------------------------------------------
// CSR build step 3: scatter src indices into dst-sorted slots
// ---------------------------------------------------------------------------
__global__ void fill_kernel(const int* __restrict__ ei, int* __restrict__ cursor,
                            int* __restrict__ csr_src)
{
    int e = blockIdx.x * 256 + threadIdx.x;
    if (e < N_EDGES) {
        int d = ei[N_EDGES + e];
        int pos = atomicAdd(&cursor[d], 1);
        csr_src[pos] = ei[e];
    }
}

// ---------------------------------------------------------------------------
// gather-mean aggregation: mean[n] = sum_{s in N(n)} x[s] / max(deg,1)
// one group of D/4 lanes per node, float4 loads (L3-resident gathers)
// ---------------------------------------------------------------------------
template<int D>
__global__ __launch_bounds__(256) void gather_mean_kernel(
    const float* __restrict__ x, const int* __restrict__ rowptr,
    const int* __restrict__ csr_src, float* __restrict__ mean)
{
    constexpr int GT = D / 4;         // lanes per node
    constexpr int NGRP = 256 / GT;    // nodes per block
    int grp = threadIdx.x / GT;
    int t   = threadIdx.x % GT;
    int n = blockIdx.x * NGRP + grp;
    if (n >= N_NODES) return;
    int e0 = rowptr[n], e1 = rowptr[n + 1];
    const float4* xv = (const float4*)x;
    float4 acc = make_float4(0.f, 0.f, 0.f, 0.f);
    int e = e0;
    for (; e + 1 < e1; e += 2) {
        int s0 = csr_src[e], s1 = csr_src[e + 1];
        float4 v0 = xv[(size_t)s0 * GT + t];
        float4 v1 = xv[(size_t)s1 * GT + t];
        acc.x += v0.x + v1.x; acc.y += v0.y + v1.y;
        acc.z += v0.z + v1.z; acc.w += v0.w + v1.w;
    }
    if (e < e1) {
        int s0 = csr_src[e];
        float4 v0 = xv[(size_t)s0 * GT + t];
        acc.x += v0.x; acc.y += v0.y; acc.z += v0.z; acc.w += v0.w;
    }
    float inv = 1.0f / fmaxf((float)(e1 - e0), 1.0f);
    acc.x *= inv; acc.y *= inv; acc.z *= inv; acc.w *= inv;
    ((float4*)mean)[(size_t)n * GT + t] = acc;
}

// ---------------------------------------------------------------------------
// fused GEMM: t[n,j] = sum_k mean[n,k]*Wl[k,j] + x[n,k]*Wr[k,j] + bl[j]
//             r[n,j] = sum_k x[n,k]*Wp[k,j] + bp[j]
// ---------------------------------------------------------------------------
template<int K, int HOUT, int RB>
__global__ __launch_bounds__(HOUT) void gemm_fused(
    const float* __restrict__ mean, const float* __restrict__ xin,
    const float* __restrict__ Wl, const float* __restrict__ bl,
    const float* __restrict__ Wr,
    const float* __restrict__ Wp, const float* __restrict__ bp,
    float* __restrict__ tout, float* __restrict__ rout)
{
    __shared__ float ms[RB][K];
    __shared__ float xs[RB][K];
    int n0 = blockIdx.x * RB;
    int tid = threadIdx.x;
    for (int i = tid; i < RB * K; i += HOUT) {
        int r = i / K, k = i % K;
        int n = n0 + r;
        float xv = 0.f, mv = 0.f;
        if (n < N_NODES) {
            xv = xin[(size_t)n * K + k];
            mv = mean[(size_t)n * K + k];
        }
        xs[r][k] = xv;
        ms[r][k] = mv;
    }
    __syncthreads();

    int j = tid;
    float acc_t[RB], acc_r[RB];
    float blj = bl[j], bpj = bp[j];
    #pragma unroll
    for (int r = 0; r < RB; ++r) { acc_t[r] = blj; acc_r[r] = bpj; }

    for (int k = 0; k < K; ++k) {
        float wl = Wl[k * HOUT + j];
        float wr = Wr[k * HOUT + j];
        float wp = Wp[k * HOUT + j];
        #pragma unroll
        for (int r = 0; r < RB; ++r) {
            acc_t[r] += ms[r][k] * wl + xs[r][k] * wr;
            acc_r[r] += xs[r][k] * wp;
        }
    }
    #pragma unroll
    for (int r = 0; r < RB; ++r) {
        int n = n0 + r;
        if (n < N_NODES) {
            tout[(size_t)n * HOUT + j] = acc_t[r];
            rout[(size_t)n * HOUT + j] = acc_r[r];
        }
    }
}

// ---------------------------------------------------------------------------
// per-row L2 normalize (in place) + accumulate column sum / sumsq for BN
// ---------------------------------------------------------------------------
template<int H>
__global__ __launch_bounds__(H) void rownorm_stats(
    float* __restrict__ t, float* __restrict__ colsum, float* __restrict__ colsumsq)
{
    __shared__ float part[H / 64];
    int j = threadIdx.x;
    int wave = j >> 6, lane = j & 63;
    float cs = 0.f, cq = 0.f;
    for (int n = blockIdx.x; n < N_NODES; n += gridDim.x) {
        float v = t[(size_t)n * H + j];
        float s = v * v;
        #pragma unroll
        for (int off = 32; off > 0; off >>= 1) s += __shfl_xor(s, off);
        if (lane == 0) part[wave] = s;
        __syncthreads();
        float tot = 0.f;
        #pragma unroll
        for (int w = 0; w < H / 64; ++w) tot += part[w];
        float inv = 1.0f / fmaxf(sqrtf(tot), 1e-12f);
        v *= inv;
        t[(size_t)n * H + j] = v;
        cs += v;
        cq += v * v;
        __syncthreads();
    }
    atomicAdd(&colsum[j], cs);
    atomicAdd(&colsumsq[j], cq);
}

// ---------------------------------------------------------------------------
template<int H>
__global__ void bn_finalize(const float* __restrict__ colsum, const float* __restrict__ colsumsq,
                            const float* __restrict__ g, const float* __restrict__ be,
                            float* __restrict__ scale, float* __restrict__ shift)
{
    int j = threadIdx.x;
    if (j < H) {
        float mu = colsum[j] / (float)N_NODES;
        float var = colsumsq[j] / (float)N_NODES - mu * mu;
        float sc = g[j] * rsqrtf(var + BN_EPS);
        scale[j] = sc;
        shift[j] = be[j] - mu * sc;
    }
}

// ---------------------------------------------------------------------------
// layer 0 epilogue: h = relu(t*scale+shift) + r   (in place over t)
// ---------------------------------------------------------------------------
__global__ void ew0_kernel(float* __restrict__ t, const float* __restrict__ r,
                           const float* __restrict__ scale, const float* __restrict__ shift)
{
    long long gid = (long long)blockIdx.x * blockDim.x + threadIdx.x;
    if (gid >= (long long)N_NODES * H1_) return;
    int j = (int)(gid & (H1_ - 1));
    float v = t[gid] * scale[j] + shift[j];
    t[gid] = fmaxf(v, 0.f) + r[gid];
}

// ---------------------------------------------------------------------------
// layer 1 epilogue fused with mean-pool scatter (batch sorted -> run-length)
// ---------------------------------------------------------------------------
__global__ __launch_bounds__(H2_) void ew1_pool_kernel(
    const float* __restrict__ t, const float* __restrict__ r,
    const float* __restrict__ scale, const float* __restrict__ shift,
    const int* __restrict__ batch,
    float* __restrict__ pooled, float* __restrict__ pcnt)
{
    int j = threadIdx.x;                // 0..127 (column)
    int n0 = blockIdx.x * 64;
    int nend = min(n0 + 64, N_NODES);
    float acc = 0.f, cacc = 0.f;
    int run = -1;
    float sc = scale[j], sh = shift[j];
    for (int n = n0; n < nend; ++n) {
        int b = batch[n];
        if (b != run) {
            if (run >= 0) {
                atomicAdd(&pooled[run * H2_ + j], acc);
                if (j == 0) atomicAdd(&pcnt[run], cacc);
            }
            run = b; acc = 0.f; cacc = 0.f;
        }
        float v = t[(size_t)n * H2_ + j] * sc + sh;
        v = fmaxf(v, 0.f) + r[(size_t)n * H2_ + j];
        acc += v;
        cacc += 1.f;
    }
    if (run >= 0) {
        atomicAdd(&pooled[run * H2_ + j], acc);
        if (j == 0) atomicAdd(&pcnt[run], cacc);
    }
}

// ---------------------------------------------------------------------------
__global__ void pool_fin_kernel(const float* __restrict__ pooled, const float* __restrict__ pcnt,
                                float* __restrict__ emb, float* __restrict__ emb_out)
{
    int gid = blockIdx.x * blockDim.x + threadIdx.x;
    if (gid < NG * H2_) {
        int g = gid >> 7;
        float v = pooled[gid] / fmaxf(pcnt[g], 1.0f);
        emb[gid] = v;
        emb_out[gid] = v;
    }
}

// ---------------------------------------------------------------------------
// classifier MLP, single block (BN over 64 rows is thread-local per column)
// ---------------------------------------------------------------------------
__global__ __launch_bounds__(256) void classifier_kernel(
    const float* __restrict__ emb,
    const float* __restrict__ Wc0, const float* __restrict__ bc0,
    const float* __restrict__ gc0, const float* __restrict__ bec0,
    const float* __restrict__ Wc1, const float* __restrict__ bc1,
    const float* __restrict__ gc1, const float* __restrict__ bec1,
    const float* __restrict__ Wc2, const float* __restrict__ bc2,
    float* __restrict__ logits)
{
    __shared__ float es[NG][H2_];
    __shared__ float z0[NG][256];
    int tid = threadIdx.x;
    for (int i = tid; i < NG * H2_; i += 256) es[i >> 7][i & 127] = emb[i];
    __syncthreads();

    {
        int j = tid;
        float acc[NG];
        float b = bc0[j];
        #pragma unroll
        for (int r2 = 0; r2 < NG; ++r2) acc[r2] = b;
        for (int k = 0; k < H2_; ++k) {
            float w = Wc0[k * 256 + j];
            #pragma unroll
            for (int r2 = 0; r2 < NG; ++r2) acc[r2] += es[r2][k] * w;
        }
        float mu = 0.f;
        #pragma unroll
        for (int r2 = 0; r2 < NG; ++r2) mu += acc[r2];
        mu *= (1.0f / NG);
        float var = 0.f;
        #pragma unroll
        for (int r2 = 0; r2 < NG; ++r2) { float d = acc[r2] - mu; var += d * d; }
        var *= (1.0f / NG);
        float sc = gc0[j] * rsqrtf(var + BN_EPS);
        float sh = bec0[j] - mu * sc;
        #pragma unroll
        for (int r2 = 0; r2 < NG; ++r2) z0[r2][j] = fmaxf(acc[r2] * sc + sh, 0.f);
    }
    __syncthreads();

    if (tid < H2_) {
        int j = tid;
        float acc[NG];
        float b = bc1[j];
        #pragma unroll
        for (int r2 = 0; r2 < NG; ++r2) acc[r2] = b;
        for (int k = 0; k < 256; ++k) {
            float w = Wc1[k * H2_ + j];
            #pragma unroll
            for (int r2 = 0; r2 < NG; ++r2) acc[r2] += z0[r2][k] * w;
        }
        float mu = 0.f;
        #pragma unroll
        for (int r2 = 0; r2 < NG; ++r2) mu += acc[r2];
        mu *= (1.0f / NG);
        float var = 0.f;
        #pragma unroll
        for (int r2 = 0; r2 < NG; ++r2) { float d = acc[r2] - mu; var += d * d; }
        var *= (1.0f / NG);
        float sc = gc1[j] * rsqrtf(var + BN_EPS);
        float sh = bec1[j] - mu * sc;
        #pragma unroll
        for (int r2 = 0; r2 < NG; ++r2) es[r2][j] = fmaxf(acc[r2] * sc + sh, 0.f);
    }
    __syncthreads();

    if (tid < NG * NC_) {
        int r2 = tid >> 1, c = tid & 1;
        float acc = bc2[c];
        for (int k = 0; k < H2_; ++k) acc += es[r2][k] * Wc2[k * NC_ + c];
        logits[r2 * NC_ + c] = acc;
    }
}

// ---------------------------------------------------------------------------
extern "C" void kernel_launch(void* const* d_in, const int* in_sizes, int n_in,
                              void* d_out, int out_size, void* d_ws, size_t ws_size,
                              hipStream_t stream)
{
    const float* x    = (const float*)d_in[0];
    const int*   ei   = (const int*)d_in[1];
    const int*   batch= (const int*)d_in[2];
    const float* Wl0  = (const float*)d_in[3];
    const float* bl0  = (const float*)d_in[4];
    const float* Wr0  = (const float*)d_in[5];
    const float* g0   = (const float*)d_in[6];
    const float* be0  = (const float*)d_in[7];
    const float* Wl1  = (const float*)d_in[8];
    const float* bl1  = (const float*)d_in[9];
    const float* Wr1  = (const float*)d_in[10];
    const float* g1   = (const float*)d_in[11];
    const float* be1  = (const float*)d_in[12];
    const float* Wp0  = (const float*)d_in[13];
    const float* bp0  = (const float*)d_in[14];
    const float* Wp1  = (const float*)d_in[15];
    const float* bp1  = (const float*)d_in[16];
    const float* Wc0  = (const float*)d_in[17];
    const float* bc0  = (const float*)d_in[18];
    const float* gc0  = (const float*)d_in[19];
    const float* bec0 = (const float*)d_in[20];
    const float* Wc1  = (const float*)d_in[21];
    const float* bc1  = (const float*)d_in[22];
    const float* gc1  = (const float*)d_in[23];
    const float* bec1 = (const float*)d_in[24];
    const float* Wc2  = (const float*)d_in[25];
    const float* bc2  = (const float*)d_in[26];

    // ---- workspace layout (floats). Total = 38,432,768 floats = 146.6 MiB
    float* ws = (float*)d_ws;
    float* fs = ws;                         // 32768 small area
    float* colsum0   = fs;                  // 256
    float* colsumsq0 = fs + 256;            // 256
    float* colsum1   = fs + 512;            // 128
    float* colsumsq1 = fs + 640;            // 128
    float* ss0       = fs + 768;            // 512 (scale0, shift0)
    float* ss1       = fs + 1280;           // 256 (scale1, shift1)
    float* pooled    = fs + 1536;           // 8192
    float* pcnt      = fs + 9728;           // 64
    float* emb       = fs + 9792;           // 8192
    float* A  = ws + 32768;                 // 6.4M  : mean0 -> t1
    float* B  = A + 6400000;                // 12.8M : t0 -> h0
    float* C  = B + 12800000;               // 12.8M : r0 -> mean1
    float* Dd = C + 12800000;               // 6.4M  : CSR ints -> r1
    // CSR int area overlays Dd (dead before gemm1 writes r1 there)
    int* deg    = (int*)Dd;                 // 50000
    int* rowptr = deg + 50000;              // 50001
    int* cursor = rowptr + 50001;           // 50000
    int* csr    = cursor + 50000;           // 800000

    float* logits_out = (float*)d_out;
    float* emb_out    = logits_out + NG * NC_;

    // zero small stats area + degree counters
    hipMemsetAsync(fs, 0, 32768 * sizeof(float), stream);
    hipMemsetAsync(deg, 0, 50000 * sizeof(int), stream);

    // ---- CSR build (shared by both layers) ----
    degree_kernel<<<(N_EDGES + 255) / 256, 256, 0, stream>>>(ei, deg);
    scan_kernel<<<1, 1024, 0, stream>>>(deg, rowptr, cursor);
    fill_kernel<<<(N_EDGES + 255) / 256, 256, 0, stream>>>(ei, cursor, csr);

    // ---- layer 0 ----
    gather_mean_kernel<D_IN><<<(N_NODES + 7) / 8, 256, 0, stream>>>(x, rowptr, csr, A);
    gemm_fused<D_IN, H1_, 32><<<(N_NODES + 31) / 32, H1_, 0, stream>>>(
        A, x, Wl0, bl0, Wr0, Wp0, bp0, B, C);
    rownorm_stats<H1_><<<1024, H1_, 0, stream>>>(B, colsum0, colsumsq0);
    bn_finalize<H1_><<<1, H1_, 0, stream>>>(colsum0, colsumsq0, g0, be0, ss0, ss0 + 256);
    {
        long long tot = (long long)N_NODES * H1_;
        ew0_kernel<<<(int)((tot + 255) / 256), 256, 0, stream>>>(B, C, ss0, ss0 + 256);
    }

    // ---- layer 1 ----
    gather_mean_kernel<H1_><<<(N_NODES + 3) / 4, 256, 0, stream>>>(B, rowptr, csr, C);
    gemm_fused<H1_, H2_, 32><<<(N_NODES + 31) / 32, H2_, 0, stream>>>(
        C, B, Wl1, bl1, Wr1, Wp1, bp1, A, Dd);
    rownorm_stats<H2_><<<1024, H2_, 0, stream>>>(A, colsum1, colsumsq1);
    bn_finalize<H2_><<<1, H2_, 0, stream>>>(colsum1, colsumsq1, g1, be1, ss1, ss1 + 128);
    ew1_pool_kernel<<<(N_NODES + 63) / 64, H2_, 0, stream>>>(
        A, Dd, ss1, ss1 + 128, batch, pooled, pcnt);

    // ---- pooling + classifier ----
    pool_fin_kernel<<<32, 256, 0, stream>>>(pooled, pcnt, emb, emb_out);
    classifier_kernel<<<1, 256, 0, stream>>>(
        emb, Wc0, bc0, gc0, bec0, Wc1, bc1, gc1, bec1, Wc2, bc2, logits_out);
}

// Round 3
// 1421.809 us; speedup vs baseline: 1.6202x; 1.1373x over previous
//
#include <hip/hip_runtime.h>
#include <hip/hip_bf16.h>
#include <math.h>

#define N_NODES 50000
#define N_EDGES 800000
#define D_IN    128
#define H1_     256
#define H2_     128
#define NG      64
#define NC_     2
#define BN_EPS  1e-5f

__device__ __forceinline__ float bf2f(unsigned short u) {
    unsigned int v = ((unsigned int)u) << 16;
    return __uint_as_float(v);
}
__device__ __forceinline__ unsigned short f2bf(float f) {
    __hip_bfloat16 h = __float2bfloat16(f);
    return *reinterpret_cast<unsigned short*>(&h);
}

// ---------------------------------------------------------------------------
// CSR build
// ---------------------------------------------------------------------------
__global__ void degree_kernel(const int* __restrict__ ei, int* __restrict__ deg)
{
    int e = blockIdx.x * 256 + threadIdx.x;
    if (e < N_EDGES) atomicAdd(&deg[ei[N_EDGES + e]], 1);
}

__global__ __launch_bounds__(1024) void scan_kernel(const int* __restrict__ deg,
                                                    int* __restrict__ rowptr,
                                                    int* __restrict__ cursor)
{
    __shared__ int buf[1024];
    __shared__ int carry_s;
    if (threadIdx.x == 0) carry_s = 0;
    __syncthreads();
    for (int base = 0; base < N_NODES; base += 1024) {
        int i = base + threadIdx.x;
        int v = (i < N_NODES) ? deg[i] : 0;
        buf[threadIdx.x] = v;
        __syncthreads();
        for (int off = 1; off < 1024; off <<= 1) {
            int t = (threadIdx.x >= off) ? buf[threadIdx.x - off] : 0;
            __syncthreads();
            buf[threadIdx.x] += t;
            __syncthreads();
        }
        int carry = carry_s;
        int excl = carry + buf[threadIdx.x] - v;
        if (i < N_NODES) { rowptr[i] = excl; cursor[i] = excl; }
        if (i == N_NODES - 1) rowptr[N_NODES] = excl + v;
        __syncthreads();
        if (threadIdx.x == 1023) carry_s = carry + buf[1023];
        __syncthreads();
    }
}

__global__ void fill_kernel(const int* __restrict__ ei, int* __restrict__ cursor,
                            int* __restrict__ csr_src)
{
    int e = blockIdx.x * 256 + threadIdx.x;
    if (e < N_EDGES) {
        int d = ei[N_EDGES + e];
        int pos = atomicAdd(&cursor[d], 1);
        csr_src[pos] = ei[e];
    }
}

// ---------------------------------------------------------------------------
// f32 -> bf16 convert (4 elems/thread)
// ---------------------------------------------------------------------------
__global__ void conv_bf16_kernel(const float* __restrict__ in,
                                 unsigned short* __restrict__ out, int n4)
{
    int i = blockIdx.x * 256 + threadIdx.x;
    if (i < n4) {
        float4 v = ((const float4*)in)[i];
        ushort4 o;
        o.x = f2bf(v.x); o.y = f2bf(v.y); o.z = f2bf(v.z); o.w = f2bf(v.w);
        ((ushort4*)out)[i] = o;
    }
}

// ---------------------------------------------------------------------------
// gather-mean from bf16 features, f32 accumulate, f32 mean out
// ---------------------------------------------------------------------------
template<int D>
__global__ __launch_bounds__(256) void gather_mean_bf16_kernel(
    const unsigned short* __restrict__ xb, const int* __restrict__ rowptr,
    const int* __restrict__ csr_src, float* __restrict__ mean)
{
    constexpr int GT = D / 4;         // lanes per node, 4 bf16 (8B) per lane
    constexpr int NGRP = 256 / GT;
    int grp = threadIdx.x / GT;
    int t   = threadIdx.x % GT;
    int n = blockIdx.x * NGRP + grp;
    if (n >= N_NODES) return;
    int e0 = rowptr[n], e1 = rowptr[n + 1];
    const ushort4* xv = (const ushort4*)xb;
    float a0 = 0.f, a1 = 0.f, a2 = 0.f, a3 = 0.f;
    int e = e0;
    for (; e + 1 < e1; e += 2) {
        int s0 = csr_src[e], s1 = csr_src[e + 1];
        ushort4 v0 = xv[(size_t)s0 * GT + t];
        ushort4 v1 = xv[(size_t)s1 * GT + t];
        a0 += bf2f(v0.x) + bf2f(v1.x);
        a1 += bf2f(v0.y) + bf2f(v1.y);
        a2 += bf2f(v0.z) + bf2f(v1.z);
        a3 += bf2f(v0.w) + bf2f(v1.w);
    }
    if (e < e1) {
        int s0 = csr_src[e];
        ushort4 v0 = xv[(size_t)s0 * GT + t];
        a0 += bf2f(v0.x); a1 += bf2f(v0.y); a2 += bf2f(v0.z); a3 += bf2f(v0.w);
    }
    float inv = 1.0f / fmaxf((float)(e1 - e0), 1.0f);
    float4 o; o.x = a0 * inv; o.y = a1 * inv; o.z = a2 * inv; o.w = a3 * inv;
    ((float4*)mean)[(size_t)n * GT + t] = o;
}

// ---------------------------------------------------------------------------
// register-tiled f32 GEMM with fused epilogue:
//   t[n,:] = rownormalize(mean[n,:]@Wl + bl + x[n,:]@Wr)  -> tout
//   r[n,:] = x[n,:]@Wp + bp                               -> rout
//   colsum/colsumsq += per-column stats of normalized t (for BN)
// thread = 4 cols x RR rows; block = 256 threads; W=HOUT/4 threads per row
// ---------------------------------------------------------------------------
template<int K, int HOUT, int RR, int KCH>
__global__ __launch_bounds__(256) void gemm_f32_kernel(
    const float* __restrict__ mean, const float* __restrict__ xin,
    const float* __restrict__ Wl, const float* __restrict__ bl,
    const float* __restrict__ Wr,
    const float* __restrict__ Wp, const float* __restrict__ bp,
    float* __restrict__ tout, float* __restrict__ rout,
    float* __restrict__ colsum, float* __restrict__ colsumsq)
{
    constexpr int W   = HOUT / 4;     // threads per output row
    constexpr int NRG = 256 / W;      // row groups per block
    constexpr int BM  = NRG * RR;     // rows per block
    __shared__ float ms[BM][KCH];
    __shared__ float xs[BM][KCH];
    int tid = threadIdx.x;
    int jt = tid % W, rg = tid / W;
    int jc = jt * 4;
    int r0 = rg * RR;
    int n0 = blockIdx.x * BM;

    float tacc[RR][4], racc[RR][4];
    #pragma unroll
    for (int rr = 0; rr < RR; ++rr)
        #pragma unroll
        for (int c = 0; c < 4; ++c) { tacc[rr][c] = 0.f; racc[rr][c] = 0.f; }

    for (int kc = 0; kc < K; kc += KCH) {
        __syncthreads();
        for (int i = tid; i < BM * (KCH / 4); i += 256) {
            int row = i / (KCH / 4), kq = i % (KCH / 4);
            int n = n0 + row;
            float4 mv = make_float4(0.f, 0.f, 0.f, 0.f);
            float4 xv = make_float4(0.f, 0.f, 0.f, 0.f);
            if (n < N_NODES) {
                mv = *(const float4*)(mean + (size_t)n * K + kc + kq * 4);
                xv = *(const float4*)(xin  + (size_t)n * K + kc + kq * 4);
            }
            *(float4*)&ms[row][kq * 4] = mv;
            *(float4*)&xs[row][kq * 4] = xv;
        }
        __syncthreads();

        #pragma unroll 4
        for (int k = 0; k < KCH; ++k) {
            float4 wl = *(const float4*)(Wl + (size_t)(kc + k) * HOUT + jc);
            float4 wr = *(const float4*)(Wr + (size_t)(kc + k) * HOUT + jc);
            float4 wp = *(const float4*)(Wp + (size_t)(kc + k) * HOUT + jc);
            #pragma unroll
            for (int rr = 0; rr < RR; ++rr) {
                float am = ms[r0 + rr][k];
                float ax = xs[r0 + rr][k];
                tacc[rr][0] += am * wl.x + ax * wr.x;
                tacc[rr][1] += am * wl.y + ax * wr.y;
                tacc[rr][2] += am * wl.z + ax * wr.z;
                tacc[rr][3] += am * wl.w + ax * wr.w;
                racc[rr][0] += ax * wp.x;
                racc[rr][1] += ax * wp.y;
                racc[rr][2] += ax * wp.z;
                racc[rr][3] += ax * wp.w;
            }
        }
    }

    float4 blv = *(const float4*)(bl + jc);
    float4 bpv = *(const float4*)(bp + jc);
    float cs[4] = {0.f, 0.f, 0.f, 0.f}, cq[4] = {0.f, 0.f, 0.f, 0.f};

    #pragma unroll
    for (int rr = 0; rr < RR; ++rr) {
        float t0 = tacc[rr][0] + blv.x;
        float t1 = tacc[rr][1] + blv.y;
        float t2 = tacc[rr][2] + blv.z;
        float t3 = tacc[rr][3] + blv.w;
        float ssq = t0 * t0 + t1 * t1 + t2 * t2 + t3 * t3;
        #pragma unroll
        for (int off = W / 2; off >= 1; off >>= 1) ssq += __shfl_xor(ssq, off);
        float inv = 1.0f / fmaxf(sqrtf(ssq), 1e-12f);
        t0 *= inv; t1 *= inv; t2 *= inv; t3 *= inv;
        int n = n0 + r0 + rr;
        if (n < N_NODES) {
            float4 to; to.x = t0; to.y = t1; to.z = t2; to.w = t3;
            *(float4*)(tout + (size_t)n * HOUT + jc) = to;
            float4 ro;
            ro.x = racc[rr][0] + bpv.x; ro.y = racc[rr][1] + bpv.y;
            ro.z = racc[rr][2] + bpv.z; ro.w = racc[rr][3] + bpv.w;
            *(float4*)(rout + (size_t)n * HOUT + jc) = ro;
            cs[0] += t0; cs[1] += t1; cs[2] += t2; cs[3] += t3;
            cq[0] += t0 * t0; cq[1] += t1 * t1; cq[2] += t2 * t2; cq[3] += t3 * t3;
        }
    }

    // block-reduce column stats across row groups, one atomic per column
    __syncthreads();
    float* red_s = &ms[0][0];   // NRG*HOUT floats, fits in ms
    float* red_q = &xs[0][0];
    *(float4*)&red_s[rg * HOUT + jc] = *(float4*)cs;
    *(float4*)&red_q[rg * HOUT + jc] = *(float4*)cq;
    __syncthreads();
    if (rg == 0) {
        #pragma unroll
        for (int g = 1; g < NRG; ++g) {
            cs[0] += red_s[g * HOUT + jc];     cq[0] += red_q[g * HOUT + jc];
            cs[1] += red_s[g * HOUT + jc + 1]; cq[1] += red_q[g * HOUT + jc + 1];
            cs[2] += red_s[g * HOUT + jc + 2]; cq[2] += red_q[g * HOUT + jc + 2];
            cs[3] += red_s[g * HOUT + jc + 3]; cq[3] += red_q[g * HOUT + jc + 3];
        }
        atomicAdd(&colsum[jc],     cs[0]); atomicAdd(&colsumsq[jc],     cq[0]);
        atomicAdd(&colsum[jc + 1], cs[1]); atomicAdd(&colsumsq[jc + 1], cq[1]);
        atomicAdd(&colsum[jc + 2], cs[2]); atomicAdd(&colsumsq[jc + 2], cq[2]);
        atomicAdd(&colsum[jc + 3], cs[3]); atomicAdd(&colsumsq[jc + 3], cq[3]);
    }
}

// ---------------------------------------------------------------------------
template<int H>
__global__ void bn_finalize(const float* __restrict__ colsum, const float* __restrict__ colsumsq,
                            const float* __restrict__ g, const float* __restrict__ be,
                            float* __restrict__ scale, float* __restrict__ shift)
{
    int j = threadIdx.x;
    if (j < H) {
        float mu = colsum[j] / (float)N_NODES;
        float var = colsumsq[j] / (float)N_NODES - mu * mu;
        float sc = g[j] * rsqrtf(var + BN_EPS);
        scale[j] = sc;
        shift[j] = be[j] - mu * sc;
    }
}

// ---------------------------------------------------------------------------
// layer 0 epilogue: h = relu(t*scale+shift) + r ; write f32 (in place) + bf16
// vectorized x4
// ---------------------------------------------------------------------------
__global__ void ew0_kernel(float4* __restrict__ t, const float4* __restrict__ r,
                           const float* __restrict__ scale, const float* __restrict__ shift,
                           ushort4* __restrict__ h0b)
{
    int gid = blockIdx.x * 256 + threadIdx.x;
    if (gid >= N_NODES * H1_ / 4) return;
    int j4 = gid & (H1_ / 4 - 1);
    float4 sc = *(const float4*)(scale + j4 * 4);
    float4 sh = *(const float4*)(shift + j4 * 4);
    float4 tv = t[gid], rv = r[gid];
    float4 h;
    h.x = fmaxf(tv.x * sc.x + sh.x, 0.f) + rv.x;
    h.y = fmaxf(tv.y * sc.y + sh.y, 0.f) + rv.y;
    h.z = fmaxf(tv.z * sc.z + sh.z, 0.f) + rv.z;
    h.w = fmaxf(tv.w * sc.w + sh.w, 0.f) + rv.w;
    t[gid] = h;
    ushort4 hb;
    hb.x = f2bf(h.x); hb.y = f2bf(h.y); hb.z = f2bf(h.z); hb.w = f2bf(h.w);
    h0b[gid] = hb;
}

// ---------------------------------------------------------------------------
// layer 1 epilogue fused with mean-pool scatter (batch sorted -> run-length)
// ---------------------------------------------------------------------------
__global__ __launch_bounds__(H2_) void ew1_pool_kernel(
    const float* __restrict__ t, const float* __restrict__ r,
    const float* __restrict__ scale, const float* __restrict__ shift,
    const int* __restrict__ batch,
    float* __restrict__ pooled, float* __restrict__ pcnt)
{
    int j = threadIdx.x;
    int n0 = blockIdx.x * 64;
    int nend = min(n0 + 64, N_NODES);
    float acc = 0.f, cacc = 0.f;
    int run = -1;
    float sc = scale[j], sh = shift[j];
    for (int n = n0; n < nend; ++n) {
        int b = batch[n];
        if (b != run) {
            if (run >= 0) {
                atomicAdd(&pooled[run * H2_ + j], acc);
                if (j == 0) atomicAdd(&pcnt[run], cacc);
            }
            run = b; acc = 0.f; cacc = 0.f;
        }
        float v = t[(size_t)n * H2_ + j] * sc + sh;
        v = fmaxf(v, 0.f) + r[(size_t)n * H2_ + j];
        acc += v;
        cacc += 1.f;
    }
    if (run >= 0) {
        atomicAdd(&pooled[run * H2_ + j], acc);
        if (j == 0) atomicAdd(&pcnt[run], cacc);
    }
}

// ---------------------------------------------------------------------------
__global__ void pool_fin_kernel(const float* __restrict__ pooled, const float* __restrict__ pcnt,
                                float* __restrict__ emb, float* __restrict__ emb_out)
{
    int gid = blockIdx.x * blockDim.x + threadIdx.x;
    if (gid < NG * H2_) {
        int g = gid >> 7;
        float v = pooled[gid] / fmaxf(pcnt[g], 1.0f);
        emb[gid] = v;
        emb_out[gid] = v;
    }
}

// ---------------------------------------------------------------------------
// classifier MLP, single block
// ---------------------------------------------------------------------------
__global__ __launch_bounds__(256) void classifier_kernel(
    const float* __restrict__ emb,
    const float* __restrict__ Wc0, const float* __restrict__ bc0,
    const float* __restrict__ gc0, const float* __restrict__ bec0,
    const float* __restrict__ Wc1, const float* __restrict__ bc1,
    const float* __restrict__ gc1, const float* __restrict__ bec1,
    const float* __restrict__ Wc2, const float* __restrict__ bc2,
    float* __restrict__ logits)
{
    __shared__ float es[NG][H2_];
    __shared__ float z0[NG][256];
    int tid = threadIdx.x;
    for (int i = tid; i < NG * H2_; i += 256) es[i >> 7][i & 127] = emb[i];
    __syncthreads();

    {
        int j = tid;
        float acc[NG];
        float b = bc0[j];
        #pragma unroll
        for (int r2 = 0; r2 < NG; ++r2) acc[r2] = b;
        for (int k = 0; k < H2_; ++k) {
            float w = Wc0[k * 256 + j];
            #pragma unroll
            for (int r2 = 0; r2 < NG; ++r2) acc[r2] += es[r2][k] * w;
        }
        float mu = 0.f;
        #pragma unroll
        for (int r2 = 0; r2 < NG; ++r2) mu += acc[r2];
        mu *= (1.0f / NG);
        float var = 0.f;
        #pragma unroll
        for (int r2 = 0; r2 < NG; ++r2) { float d = acc[r2] - mu; var += d * d; }
        var *= (1.0f / NG);
        float sc = gc0[j] * rsqrtf(var + BN_EPS);
        float sh = bec0[j] - mu * sc;
        #pragma unroll
        for (int r2 = 0; r2 < NG; ++r2) z0[r2][j] = fmaxf(acc[r2] * sc + sh, 0.f);
    }
    __syncthreads();

    if (tid < H2_) {
        int j = tid;
        float acc[NG];
        float b = bc1[j];
        #pragma unroll
        for (int r2 = 0; r2 < NG; ++r2) acc[r2] = b;
        for (int k = 0; k < 256; ++k) {
            float w = Wc1[k * H2_ + j];
            #pragma unroll
            for (int r2 = 0; r2 < NG; ++r2) acc[r2] += z0[r2][k] * w;
        }
        float mu = 0.f;
        #pragma unroll
        for (int r2 = 0; r2 < NG; ++r2) mu += acc[r2];
        mu *= (1.0f / NG);
        float var = 0.f;
        #pragma unroll
        for (int r2 = 0; r2 < NG; ++r2) { float d = acc[r2] - mu; var += d * d; }
        var *= (1.0f / NG);
        float sc = gc1[j] * rsqrtf(var + BN_EPS);
        float sh = bec1[j] - mu * sc;
        #pragma unroll
        for (int r2 = 0; r2 < NG; ++r2) es[r2][j] = fmaxf(acc[r2] * sc + sh, 0.f);
    }
    __syncthreads();

    if (tid < NG * NC_) {
        int r2 = tid >> 1, c = tid & 1;
        float acc = bc2[c];
        for (int k = 0; k < H2_; ++k) acc += es[r2][k] * Wc2[k * NC_ + c];
        logits[r2 * NC_ + c] = acc;
    }
}

// ---------------------------------------------------------------------------
extern "C" void kernel_launch(void* const* d_in, const int* in_sizes, int n_in,
                              void* d_out, int out_size, void* d_ws, size_t ws_size,
                              hipStream_t stream)
{
    const float* x    = (const float*)d_in[0];
    const int*   ei   = (const int*)d_in[1];
    const int*   batch= (const int*)d_in[2];
    const float* Wl0  = (const float*)d_in[3];
    const float* bl0  = (const float*)d_in[4];
    const float* Wr0  = (const float*)d_in[5];
    const float* g0   = (const float*)d_in[6];
    const float* be0  = (const float*)d_in[7];
    const float* Wl1  = (const float*)d_in[8];
    const float* bl1  = (const float*)d_in[9];
    const float* Wr1  = (const float*)d_in[10];
    const float* g1   = (const float*)d_in[11];
    const float* be1  = (const float*)d_in[12];
    const float* Wp0  = (const float*)d_in[13];
    const float* bp0  = (const float*)d_in[14];
    const float* Wp1  = (const float*)d_in[15];
    const float* bp1  = (const float*)d_in[16];
    const float* Wc0  = (const float*)d_in[17];
    const float* bc0  = (const float*)d_in[18];
    const float* gc0  = (const float*)d_in[19];
    const float* bec0 = (const float*)d_in[20];
    const float* Wc1  = (const float*)d_in[21];
    const float* bc1  = (const float*)d_in[22];
    const float* gc1  = (const float*)d_in[23];
    const float* bec1 = (const float*)d_in[24];
    const float* Wc2  = (const float*)d_in[25];
    const float* bc2  = (const float*)d_in[26];

    // ---- workspace layout (floats). Total = 38,432,768 floats = 146.6 MiB
    float* ws = (float*)d_ws;
    float* fs = ws;                         // 32768 small area
    float* colsum0   = fs;                  // 256
    float* colsumsq0 = fs + 256;            // 256
    float* colsum1   = fs + 512;            // 128
    float* colsumsq1 = fs + 640;            // 128
    float* ss0       = fs + 768;            // 512 (scale0, shift0)
    float* ss1       = fs + 1280;           // 256 (scale1, shift1)
    float* pooled    = fs + 1536;           // 8192
    float* pcnt      = fs + 9728;           // 64
    float* emb       = fs + 9792;           // 8192
    float* A  = ws + 32768;                 // 6.4M  : mean0 -> h0b(bf16) -> t1
    float* B  = A + 6400000;                // 12.8M : t0 -> h0
    float* C  = B + 12800000;               // 12.8M : r0 -> mean1
    float* Dd = C + 12800000;               // 6.4M  : CSR ints + xb(bf16) -> r1
    int* deg    = (int*)Dd;                 // 50000
    int* rowptr = deg + 50000;              // 50001
    int* cursor = rowptr + 50001;           // 50000
    int* csr    = cursor + 50000;           // 800000  (ends at 950,001 ints)
    unsigned short* xb  = (unsigned short*)(Dd + 1000000);  // 6.4M bf16 (3.2M fl)
    unsigned short* h0b = (unsigned short*)A;               // 12.8M bf16 (6.4M fl)

    float* logits_out = (float*)d_out;
    float* emb_out    = logits_out + NG * NC_;

    hipMemsetAsync(fs, 0, 32768 * sizeof(float), stream);
    hipMemsetAsync(deg, 0, 50000 * sizeof(int), stream);

    // ---- CSR build + bf16 x ----
    degree_kernel<<<(N_EDGES + 255) / 256, 256, 0, stream>>>(ei, deg);
    scan_kernel<<<1, 1024, 0, stream>>>(deg, rowptr, cursor);
    fill_kernel<<<(N_EDGES + 255) / 256, 256, 0, stream>>>(ei, cursor, csr);
    conv_bf16_kernel<<<(N_NODES * D_IN / 4 + 255) / 256, 256, 0, stream>>>(x, xb, N_NODES * D_IN / 4);

    // ---- layer 0 ----
    gather_mean_bf16_kernel<D_IN><<<(N_NODES + 7) / 8, 256, 0, stream>>>(xb, rowptr, csr, A);
    gemm_f32_kernel<D_IN, H1_, 4, 128><<<N_NODES / 16, 256, 0, stream>>>(
        A, x, Wl0, bl0, Wr0, Wp0, bp0, B, C, colsum0, colsumsq0);
    bn_finalize<H1_><<<1, H1_, 0, stream>>>(colsum0, colsumsq0, g0, be0, ss0, ss0 + 256);
    ew0_kernel<<<(N_NODES * H1_ / 4 + 255) / 256, 256, 0, stream>>>(
        (float4*)B, (const float4*)C, ss0, ss0 + 256, (ushort4*)h0b);

    // ---- layer 1 ----
    gather_mean_bf16_kernel<H1_><<<(N_NODES + 3) / 4, 256, 0, stream>>>(h0b, rowptr, csr, C);
    gemm_f32_kernel<H1_, H2_, 4, 128><<<(N_NODES + 31) / 32, 256, 0, stream>>>(
        C, B, Wl1, bl1, Wr1, Wp1, bp1, A, Dd, colsum1, colsumsq1);
    bn_finalize<H2_><<<1, H2_, 0, stream>>>(colsum1, colsumsq1, g1, be1, ss1, ss1 + 128);
    ew1_pool_kernel<<<(N_NODES + 63) / 64, H2_, 0, stream>>>(
        A, Dd, ss1, ss1 + 128, batch, pooled, pcnt);

    // ---- pooling + classifier ----
    pool_fin_kernel<<<32, 256, 0, stream>>>(pooled, pcnt, emb, emb_out);
    classifier_kernel<<<1, 256, 0, stream>>>(
        emb, Wc0, bc0, gc0, bec0, Wc1, bc1, gc1, bec1, Wc2, bc2, logits_out);
}

// Round 4
// 773.874 us; speedup vs baseline: 2.9766x; 1.8373x over previous
//
#include <hip/hip_runtime.h>
#include <hip/hip_bf16.h>
#include <math.h>

#define N_NODES 50000
#define N_EDGES 800000
#define D_IN    128
#define H1_     256
#define H2_     128
#define NG      64
#define NC_     2
#define BN_EPS  1e-5f

typedef __attribute__((ext_vector_type(8))) short bf16x8;
typedef __attribute__((ext_vector_type(4))) float f32x4;

__device__ __forceinline__ float bf2f(unsigned short u) {
    unsigned int v = ((unsigned int)u) << 16;
    return __uint_as_float(v);
}
__device__ __forceinline__ unsigned short f2bf(float f) {
    __hip_bfloat16 h = __float2bfloat16(f);
    return *reinterpret_cast<unsigned short*>(&h);
}

// ---------------------------------------------------------------------------
// CSR build
// ---------------------------------------------------------------------------
__global__ void degree_kernel(const int* __restrict__ ei, int* __restrict__ deg)
{
    int e = blockIdx.x * 256 + threadIdx.x;
    if (e < N_EDGES) atomicAdd(&deg[ei[N_EDGES + e]], 1);
}

__global__ __launch_bounds__(1024) void scan_kernel(const int* __restrict__ deg,
                                                    int* __restrict__ rowptr,
                                                    int* __restrict__ cursor)
{
    __shared__ int buf[1024];
    __shared__ int carry_s;
    if (threadIdx.x == 0) carry_s = 0;
    __syncthreads();
    for (int base = 0; base < N_NODES; base += 1024) {
        int i = base + threadIdx.x;
        int v = (i < N_NODES) ? deg[i] : 0;
        buf[threadIdx.x] = v;
        __syncthreads();
        for (int off = 1; off < 1024; off <<= 1) {
            int t = (threadIdx.x >= off) ? buf[threadIdx.x - off] : 0;
            __syncthreads();
            buf[threadIdx.x] += t;
            __syncthreads();
        }
        int carry = carry_s;
        int excl = carry + buf[threadIdx.x] - v;
        if (i < N_NODES) { rowptr[i] = excl; cursor[i] = excl; }
        if (i == N_NODES - 1) rowptr[N_NODES] = excl + v;
        __syncthreads();
        if (threadIdx.x == 1023) carry_s = carry + buf[1023];
        __syncthreads();
    }
}

__global__ void fill_kernel(const int* __restrict__ ei, int* __restrict__ cursor,
                            int* __restrict__ csr_src)
{
    int e = blockIdx.x * 256 + threadIdx.x;
    if (e < N_EDGES) {
        int d = ei[N_EDGES + e];
        int pos = atomicAdd(&cursor[d], 1);
        csr_src[pos] = ei[e];
    }
}

// ---------------------------------------------------------------------------
// f32 -> bf16 convert (4 elems/thread)
// ---------------------------------------------------------------------------
__global__ void conv_bf16_kernel(const float* __restrict__ in,
                                 unsigned short* __restrict__ out, int n4)
{
    int i = blockIdx.x * 256 + threadIdx.x;
    if (i < n4) {
        float4 v = ((const float4*)in)[i];
        ushort4 o;
        o.x = f2bf(v.x); o.y = f2bf(v.y); o.z = f2bf(v.z); o.w = f2bf(v.w);
        ((ushort4*)out)[i] = o;
    }
}

// ---------------------------------------------------------------------------
// weight swizzle into MFMA B-fragment order, f32 -> bf16.
// wt  : combined [Wl;Wr]  (K1+K2 x HOUT), frag idx (nt*NKT_T+kt)*64+lane, 8 elems
// wrp : Wp (K2 x HOUT), frag idx (nt*NKT_R+kt)*64+lane, 8 elems
// element j of a fragment = W[kt*32 + (lane>>4)*8 + j][nt*16 + (lane&15)]
// ---------------------------------------------------------------------------
template<int K1, int K2, int HOUT>
__global__ void wswz_kernel(const float* __restrict__ Wl, const float* __restrict__ Wr,
                            const float* __restrict__ Wp,
                            unsigned short* __restrict__ wt, unsigned short* __restrict__ wrp)
{
    constexpr int NKT_T = (K1 + K2) / 32;
    constexpr int NKT_R = K2 / 32;
    constexpr int NNT = HOUT / 16;
    const int total_t = NNT * NKT_T * 64;
    const int total_r = NNT * NKT_R * 64;
    int idx = blockIdx.x * 256 + threadIdx.x;
    if (idx < total_t) {
        int lane = idx & 63, f = idx >> 6;
        int kt = f % NKT_T, nt = f / NKT_T;
        int col = nt * 16 + (lane & 15);
        int k0 = kt * 32 + (lane >> 4) * 8;
        ushort4 lo, hi;
        unsigned short o[8];
        #pragma unroll
        for (int j = 0; j < 8; ++j) {
            int k = k0 + j;
            float v = (k < K1) ? Wl[(size_t)k * HOUT + col]
                               : Wr[(size_t)(k - K1) * HOUT + col];
            o[j] = f2bf(v);
        }
        lo.x = o[0]; lo.y = o[1]; lo.z = o[2]; lo.w = o[3];
        hi.x = o[4]; hi.y = o[5]; hi.z = o[6]; hi.w = o[7];
        ((ushort4*)wt)[idx * 2]     = lo;
        ((ushort4*)wt)[idx * 2 + 1] = hi;
    } else if (idx < total_t + total_r) {
        int i2 = idx - total_t;
        int lane = i2 & 63, f = i2 >> 6;
        int kt = f % NKT_R, nt = f / NKT_R;
        int col = nt * 16 + (lane & 15);
        int k0 = kt * 32 + (lane >> 4) * 8;
        ushort4 lo, hi;
        unsigned short o[8];
        #pragma unroll
        for (int j = 0; j < 8; ++j)
            o[j] = f2bf(Wp[(size_t)(k0 + j) * HOUT + col]);
        lo.x = o[0]; lo.y = o[1]; lo.z = o[2]; lo.w = o[3];
        hi.x = o[4]; hi.y = o[5]; hi.z = o[6]; hi.w = o[7];
        ((ushort4*)wrp)[i2 * 2]     = lo;
        ((ushort4*)wrp)[i2 * 2 + 1] = hi;
    }
}

// ---------------------------------------------------------------------------
// gather-mean from bf16 features, f32 accumulate, bf16 mean out
// ---------------------------------------------------------------------------
template<int D>
__global__ __launch_bounds__(256) void gather_mean_bf16_kernel(
    const unsigned short* __restrict__ xb, const int* __restrict__ rowptr,
    const int* __restrict__ csr_src, unsigned short* __restrict__ mean)
{
    constexpr int GT = D / 4;         // lanes per node, 4 bf16 (8B) per lane
    constexpr int NGRP = 256 / GT;
    int grp = threadIdx.x / GT;
    int t   = threadIdx.x % GT;
    int n = blockIdx.x * NGRP + grp;
    if (n >= N_NODES) return;
    int e0 = rowptr[n], e1 = rowptr[n + 1];
    const ushort4* xv = (const ushort4*)xb;
    float a0 = 0.f, a1 = 0.f, a2 = 0.f, a3 = 0.f;
    int e = e0;
    for (; e + 1 < e1; e += 2) {
        int s0 = csr_src[e], s1 = csr_src[e + 1];
        ushort4 v0 = xv[(size_t)s0 * GT + t];
        ushort4 v1 = xv[(size_t)s1 * GT + t];
        a0 += bf2f(v0.x) + bf2f(v1.x);
        a1 += bf2f(v0.y) + bf2f(v1.y);
        a2 += bf2f(v0.z) + bf2f(v1.z);
        a3 += bf2f(v0.w) + bf2f(v1.w);
    }
    if (e < e1) {
        int s0 = csr_src[e];
        ushort4 v0 = xv[(size_t)s0 * GT + t];
        a0 += bf2f(v0.x); a1 += bf2f(v0.y); a2 += bf2f(v0.z); a3 += bf2f(v0.w);
    }
    float inv = 1.0f / fmaxf((float)(e1 - e0), 1.0f);
    ushort4 o;
    o.x = f2bf(a0 * inv); o.y = f2bf(a1 * inv);
    o.z = f2bf(a2 * inv); o.w = f2bf(a3 * inv);
    ((ushort4*)mean)[(size_t)n * GT + t] = o;
}

// ---------------------------------------------------------------------------
// MFMA GEMM, fused epilogue:
//   t[n,:] = rownormalize([mean|x][n,:] @ [Wl;Wr] + bl) -> tout (f32)
//   r[n,:] = x[n,:] @ Wp + bp                           -> rout (f32 or bf16)
//   colsum/colsumsq += column stats of normalized t
// block = 256 threads = 4 waves; wave owns 16 rows; BM=64 rows/block.
// A-fragments live in VGPRs; B pre-swizzled (wt/wrp); acc in registers.
// C/D layout (gfx950 16x16x32): col=lane&15, row=(lane>>4)*4+reg  [m89]
// A: lane holds A[lane&15][kt*32+(lane>>4)*8 + 0..7]
// ---------------------------------------------------------------------------
template<int K1, int K2, int HOUT, bool R_BF16>
__global__ __launch_bounds__(256) void gemm_mfma_kernel(
    const unsigned short* __restrict__ meanb,   // [N][K1] bf16
    const unsigned short* __restrict__ selfb,   // [N][K2] bf16
    const unsigned short* __restrict__ wt,      // swizzled [Wl;Wr]
    const unsigned short* __restrict__ wrp,     // swizzled Wp
    const float* __restrict__ bl, const float* __restrict__ bp,
    float* __restrict__ tout,
    void* __restrict__ rout,
    float* __restrict__ colsum, float* __restrict__ colsumsq)
{
    constexpr int NKT_T = (K1 + K2) / 32;
    constexpr int NKT_R = K2 / 32;
    constexpr int NKT_M = K1 / 32;
    constexpr int NNT   = HOUT / 16;
    __shared__ float sred_s[4][HOUT];
    __shared__ float sred_q[4][HOUT];

    int tid = threadIdx.x;
    int w = tid >> 6, lane = tid & 63;
    int lm = lane & 15, kq = lane >> 4;
    int arow = blockIdx.x * 64 + w * 16 + lm;          // row this lane LOADS
    int lrow = (arow < N_NODES) ? arow : (N_NODES - 1);

    // ---- A fragments (registers) ----
    bf16x8 af[NKT_T];
    {
        const unsigned short* mrow = meanb + (size_t)lrow * K1 + kq * 8;
        const unsigned short* srow = selfb + (size_t)lrow * K2 + kq * 8;
        #pragma unroll
        for (int kt = 0; kt < NKT_M; ++kt)
            af[kt] = *(const bf16x8*)(mrow + kt * 32);
        #pragma unroll
        for (int kt = 0; kt < NKT_R; ++kt)
            af[NKT_M + kt] = *(const bf16x8*)(srow + kt * 32);
    }

    int orow0 = blockIdx.x * 64 + w * 16 + kq * 4;     // rows this lane OWNS (+reg)
    f32x4 tv[NNT];
    float ssq[4] = {0.f, 0.f, 0.f, 0.f};

    #pragma unroll
    for (int nt = 0; nt < NNT; ++nt) {
        // t = [mean|x] @ [Wl;Wr]
        f32x4 acc = {0.f, 0.f, 0.f, 0.f};
        #pragma unroll
        for (int kt = 0; kt < NKT_T; ++kt) {
            bf16x8 bw = *(const bf16x8*)(wt + ((size_t)(nt * NKT_T + kt) * 64 + lane) * 8);
            acc = __builtin_amdgcn_mfma_f32_16x16x32_bf16(af[kt], bw, acc, 0, 0, 0);
        }
        float blj = bl[nt * 16 + lm];
        #pragma unroll
        for (int r = 0; r < 4; ++r) {
            acc[r] += blj;
            ssq[r] += acc[r] * acc[r];
        }
        tv[nt] = acc;

        // r = x @ Wp  (store immediately)
        f32x4 racc = {0.f, 0.f, 0.f, 0.f};
        #pragma unroll
        for (int kt = 0; kt < NKT_R; ++kt) {
            bf16x8 bw = *(const bf16x8*)(wrp + ((size_t)(nt * NKT_R + kt) * 64 + lane) * 8);
            racc = __builtin_amdgcn_mfma_f32_16x16x32_bf16(af[NKT_M + kt], bw, racc, 0, 0, 0);
        }
        float bpj = bp[nt * 16 + lm];
        #pragma unroll
        for (int r = 0; r < 4; ++r) {
            int orow = orow0 + r;
            if (orow < N_NODES) {
                float v = racc[r] + bpj;
                if (R_BF16)
                    ((unsigned short*)rout)[(size_t)orow * HOUT + nt * 16 + lm] = f2bf(v);
                else
                    ((float*)rout)[(size_t)orow * HOUT + nt * 16 + lm] = v;
            }
        }
    }

    // ---- row L2-norm: reduce ssq over the 16 col-lanes (same kq group) ----
    #pragma unroll
    for (int off = 1; off <= 8; off <<= 1)
        #pragma unroll
        for (int r = 0; r < 4; ++r)
            ssq[r] += __shfl_xor(ssq[r], off);
    float inv[4];
    #pragma unroll
    for (int r = 0; r < 4; ++r)
        inv[r] = 1.0f / fmaxf(sqrtf(ssq[r]), 1e-12f);

    // ---- normalize, store t, accumulate BN column stats ----
    #pragma unroll
    for (int nt = 0; nt < NNT; ++nt) {
        float cs = 0.f, cq = 0.f;
        #pragma unroll
        for (int r = 0; r < 4; ++r) {
            int orow = orow0 + r;
            float v = tv[nt][r] * inv[r];
            if (orow < N_NODES) {
                tout[(size_t)orow * HOUT + nt * 16 + lm] = v;
                cs += v; cq += v * v;
            }
        }
        // reduce over the 4 kq groups (row dimension)
        cs += __shfl_xor(cs, 16); cs += __shfl_xor(cs, 32);
        cq += __shfl_xor(cq, 16); cq += __shfl_xor(cq, 32);
        if (kq == 0) {
            sred_s[w][nt * 16 + lm] = cs;
            sred_q[w][nt * 16 + lm] = cq;
        }
    }
    __syncthreads();
    if (tid < HOUT) {
        float s = sred_s[0][tid] + sred_s[1][tid] + sred_s[2][tid] + sred_s[3][tid];
        float q = sred_q[0][tid] + sred_q[1][tid] + sred_q[2][tid] + sred_q[3][tid];
        atomicAdd(&colsum[tid], s);
        atomicAdd(&colsumsq[tid], q);
    }
}

// ---------------------------------------------------------------------------
template<int H>
__global__ void bn_finalize(const float* __restrict__ colsum, const float* __restrict__ colsumsq,
                            const float* __restrict__ g, const float* __restrict__ be,
                            float* __restrict__ scale, float* __restrict__ shift)
{
    int j = threadIdx.x;
    if (j < H) {
        float mu = colsum[j] / (float)N_NODES;
        float var = colsumsq[j] / (float)N_NODES - mu * mu;
        float sc = g[j] * rsqrtf(var + BN_EPS);
        scale[j] = sc;
        shift[j] = be[j] - mu * sc;
    }
}

// ---------------------------------------------------------------------------
// layer 0 epilogue: h0b = bf16( relu(t*scale+shift) + r0b )
// ---------------------------------------------------------------------------
__global__ void ew0_kernel(const float4* __restrict__ t, const ushort4* __restrict__ rb,
                           const float* __restrict__ scale, const float* __restrict__ shift,
                           ushort4* __restrict__ h0b)
{
    int gid = blockIdx.x * 256 + threadIdx.x;
    if (gid >= N_NODES * H1_ / 4) return;
    int j4 = gid & (H1_ / 4 - 1);
    float4 sc = *(const float4*)(scale + j4 * 4);
    float4 sh = *(const float4*)(shift + j4 * 4);
    float4 tv = t[gid];
    ushort4 rv = rb[gid];
    ushort4 hb;
    hb.x = f2bf(fmaxf(tv.x * sc.x + sh.x, 0.f) + bf2f(rv.x));
    hb.y = f2bf(fmaxf(tv.y * sc.y + sh.y, 0.f) + bf2f(rv.y));
    hb.z = f2bf(fmaxf(tv.z * sc.z + sh.z, 0.f) + bf2f(rv.z));
    hb.w = f2bf(fmaxf(tv.w * sc.w + sh.w, 0.f) + bf2f(rv.w));
    h0b[gid] = hb;
}

// ---------------------------------------------------------------------------
// layer 1 epilogue fused with mean-pool scatter (batch sorted -> run-length)
// ---------------------------------------------------------------------------
__global__ __launch_bounds__(H2_) void ew1_pool_kernel(
    const float* __restrict__ t, const float* __restrict__ r,
    const float* __restrict__ scale, const float* __restrict__ shift,
    const int* __restrict__ batch,
    float* __restrict__ pooled, float* __restrict__ pcnt)
{
    int j = threadIdx.x;
    int n0 = blockIdx.x * 64;
    int nend = min(n0 + 64, N_NODES);
    float acc = 0.f, cacc = 0.f;
    int run = -1;
    float sc = scale[j], sh = shift[j];
    for (int n = n0; n < nend; ++n) {
        int b = batch[n];
        if (b != run) {
            if (run >= 0) {
                atomicAdd(&pooled[run * H2_ + j], acc);
                if (j == 0) atomicAdd(&pcnt[run], cacc);
            }
            run = b; acc = 0.f; cacc = 0.f;
        }
        float v = t[(size_t)n * H2_ + j] * sc + sh;
        v = fmaxf(v, 0.f) + r[(size_t)n * H2_ + j];
        acc += v;
        cacc += 1.f;
    }
    if (run >= 0) {
        atomicAdd(&pooled[run * H2_ + j], acc);
        if (j == 0) atomicAdd(&pcnt[run], cacc);
    }
}

// ---------------------------------------------------------------------------
__global__ void pool_fin_kernel(const float* __restrict__ pooled, const float* __restrict__ pcnt,
                                float* __restrict__ emb, float* __restrict__ emb_out)
{
    int gid = blockIdx.x * blockDim.x + threadIdx.x;
    if (gid < NG * H2_) {
        int g = gid >> 7;
        float v = pooled[gid] / fmaxf(pcnt[g], 1.0f);
        emb[gid] = v;
        emb_out[gid] = v;
    }
}

// ---------------------------------------------------------------------------
// classifier MLP, single block
// ---------------------------------------------------------------------------
__global__ __launch_bounds__(256) void classifier_kernel(
    const float* __restrict__ emb,
    const float* __restrict__ Wc0, const float* __restrict__ bc0,
    const float* __restrict__ gc0, const float* __restrict__ bec0,
    const float* __restrict__ Wc1, const float* __restrict__ bc1,
    const float* __restrict__ gc1, const float* __restrict__ bec1,
    const float* __restrict__ Wc2, const float* __restrict__ bc2,
    float* __restrict__ logits)
{
    __shared__ float es[NG][H2_];
    __shared__ float z0[NG][256];
    int tid = threadIdx.x;
    for (int i = tid; i < NG * H2_; i += 256) es[i >> 7][i & 127] = emb[i];
    __syncthreads();

    {
        int j = tid;
        float acc[NG];
        float b = bc0[j];
        #pragma unroll
        for (int r2 = 0; r2 < NG; ++r2) acc[r2] = b;
        for (int k = 0; k < H2_; ++k) {
            float w = Wc0[k * 256 + j];
            #pragma unroll
            for (int r2 = 0; r2 < NG; ++r2) acc[r2] += es[r2][k] * w;
        }
        float mu = 0.f;
        #pragma unroll
        for (int r2 = 0; r2 < NG; ++r2) mu += acc[r2];
        mu *= (1.0f / NG);
        float var = 0.f;
        #pragma unroll
        for (int r2 = 0; r2 < NG; ++r2) { float d = acc[r2] - mu; var += d * d; }
        var *= (1.0f / NG);
        float sc = gc0[j] * rsqrtf(var + BN_EPS);
        float sh = bec0[j] - mu * sc;
        #pragma unroll
        for (int r2 = 0; r2 < NG; ++r2) z0[r2][j] = fmaxf(acc[r2] * sc + sh, 0.f);
    }
    __syncthreads();

    if (tid < H2_) {
        int j = tid;
        float acc[NG];
        float b = bc1[j];
        #pragma unroll
        for (int r2 = 0; r2 < NG; ++r2) acc[r2] = b;
        for (int k = 0; k < 256; ++k) {
            float w = Wc1[k * H2_ + j];
            #pragma unroll
            for (int r2 = 0; r2 < NG; ++r2) acc[r2] += z0[r2][k] * w;
        }
        float mu = 0.f;
        #pragma unroll
        for (int r2 = 0; r2 < NG; ++r2) mu += acc[r2];
        mu *= (1.0f / NG);
        float var = 0.f;
        #pragma unroll
        for (int r2 = 0; r2 < NG; ++r2) { float d = acc[r2] - mu; var += d * d; }
        var *= (1.0f / NG);
        float sc = gc1[j] * rsqrtf(var + BN_EPS);
        float sh = bec1[j] - mu * sc;
        #pragma unroll
        for (int r2 = 0; r2 < NG; ++r2) es[r2][j] = fmaxf(acc[r2] * sc + sh, 0.f);
    }
    __syncthreads();

    if (tid < NG * NC_) {
        int r2 = tid >> 1, c = tid & 1;
        float acc = bc2[c];
        for (int k = 0; k < H2_; ++k) acc += es[r2][k] * Wc2[k * NC_ + c];
        logits[r2 * NC_ + c] = acc;
    }
}

// ---------------------------------------------------------------------------
extern "C" void kernel_launch(void* const* d_in, const int* in_sizes, int n_in,
                              void* d_out, int out_size, void* d_ws, size_t ws_size,
                              hipStream_t stream)
{
    const float* x    = (const float*)d_in[0];
    const int*   ei   = (const int*)d_in[1];
    const int*   batch= (const int*)d_in[2];
    const float* Wl0  = (const float*)d_in[3];
    const float* bl0  = (const float*)d_in[4];
    const float* Wr0  = (const float*)d_in[5];
    const float* g0   = (const float*)d_in[6];
    const float* be0  = (const float*)d_in[7];
    const float* Wl1  = (const float*)d_in[8];
    const float* bl1  = (const float*)d_in[9];
    const float* Wr1  = (const float*)d_in[10];
    const float* g1   = (const float*)d_in[11];
    const float* be1  = (const float*)d_in[12];
    const float* Wp0  = (const float*)d_in[13];
    const float* bp0  = (const float*)d_in[14];
    const float* Wp1  = (const float*)d_in[15];
    const float* bp1  = (const float*)d_in[16];
    const float* Wc0  = (const float*)d_in[17];
    const float* bc0  = (const float*)d_in[18];
    const float* gc0  = (const float*)d_in[19];
    const float* bec0 = (const float*)d_in[20];
    const float* Wc1  = (const float*)d_in[21];
    const float* bc1  = (const float*)d_in[22];
    const float* gc1  = (const float*)d_in[23];
    const float* bec1 = (const float*)d_in[24];
    const float* Wc2  = (const float*)d_in[25];
    const float* bc2  = (const float*)d_in[26];

    // ---- workspace layout (float units). Total = 33,131,072 fl = 126.4 MiB
    float* ws = (float*)d_ws;
    float* fs = ws;                              // 32768 small area
    float* colsum0   = fs;                       // 256
    float* colsumsq0 = fs + 256;                 // 256
    float* colsum1   = fs + 512;                 // 128
    float* colsumsq1 = fs + 640;                 // 128
    float* ss0       = fs + 768;                 // 512 (scale0, shift0)
    float* ss1       = fs + 1280;                // 256 (scale1, shift1)
    float* pooled    = fs + 1536;                // 8192
    float* pcnt      = fs + 9728;                // 64
    float* emb       = fs + 9792;                // 8192

    unsigned short* wsz0t = (unsigned short*)(ws + 32768);   // 65536 bf16
    unsigned short* wsz0r = (unsigned short*)(ws + 65536);   // 32768 bf16
    unsigned short* wsz1t = (unsigned short*)(ws + 81920);   // 65536 bf16
    unsigned short* wsz1r = (unsigned short*)(ws + 114688);  // 32768 bf16

    int* deg    = (int*)(ws + 131072);           // 50000
    int* rowptr = deg + 50000;                   // 50001
    int* cursor = rowptr + 50001;                // 50000
    int* csr    = cursor + 50000;                // 800000

    unsigned short* h0b    = (unsigned short*)(ws + 1131072);   // 12.8M bf16
    unsigned short* xb     = (unsigned short*)(ws + 7531072);   // 6.4M bf16
    unsigned short* meanb0 = (unsigned short*)(ws + 10731072);  // 6.4M bf16
    unsigned short* meanb1 = xb;                                // reuse (12.8M bf16)
    float* t0  = ws + 13931072;                  // 12.8M f32
    float* t1  = t0;                             // 6.4M f32 (reuse)
    float* r1  = t0 + 6400000;                   // 6.4M f32 (reuse)
    unsigned short* r0b = (unsigned short*)(ws + 26731072);     // 12.8M bf16

    float* logits_out = (float*)d_out;
    float* emb_out    = logits_out + NG * NC_;

    hipMemsetAsync(fs, 0, 32768 * sizeof(float), stream);
    hipMemsetAsync(deg, 0, 50000 * sizeof(int), stream);

    // ---- prep: CSR, bf16 x, swizzled weights ----
    degree_kernel<<<(N_EDGES + 255) / 256, 256, 0, stream>>>(ei, deg);
    scan_kernel<<<1, 1024, 0, stream>>>(deg, rowptr, cursor);
    fill_kernel<<<(N_EDGES + 255) / 256, 256, 0, stream>>>(ei, cursor, csr);
    conv_bf16_kernel<<<(N_NODES * D_IN / 4 + 255) / 256, 256, 0, stream>>>(
        x, xb, N_NODES * D_IN / 4);
    wswz_kernel<D_IN, D_IN, H1_><<<48, 256, 0, stream>>>(Wl0, Wr0, Wp0, wsz0t, wsz0r);
    wswz_kernel<H1_, H1_, H2_><<<48, 256, 0, stream>>>(Wl1, Wr1, Wp1, wsz1t, wsz1r);

    // ---- layer 0 ----
    gather_mean_bf16_kernel<D_IN><<<(N_NODES + 7) / 8, 256, 0, stream>>>(
        xb, rowptr, csr, meanb0);
    gemm_mfma_kernel<D_IN, D_IN, H1_, true><<<(N_NODES + 63) / 64, 256, 0, stream>>>(
        meanb0, xb, wsz0t, wsz0r, bl0, bp0, t0, r0b, colsum0, colsumsq0);
    bn_finalize<H1_><<<1, H1_, 0, stream>>>(colsum0, colsumsq0, g0, be0, ss0, ss0 + 256);
    ew0_kernel<<<(N_NODES * H1_ / 4 + 255) / 256, 256, 0, stream>>>(
        (const float4*)t0, (const ushort4*)r0b, ss0, ss0 + 256, (ushort4*)h0b);

    // ---- layer 1 ----
    gather_mean_bf16_kernel<H1_><<<(N_NODES + 3) / 4, 256, 0, stream>>>(
        h0b, rowptr, csr, meanb1);
    gemm_mfma_kernel<H1_, H1_, H2_, false><<<(N_NODES + 63) / 64, 256, 0, stream>>>(
        meanb1, h0b, wsz1t, wsz1r, bl1, bp1, t1, r1, colsum1, colsumsq1);
    bn_finalize<H2_><<<1, H2_, 0, stream>>>(colsum1, colsumsq1, g1, be1, ss1, ss1 + 128);
    ew1_pool_kernel<<<(N_NODES + 63) / 64, H2_, 0, stream>>>(
        t1, r1, ss1, ss1 + 128, batch, pooled, pcnt);

    // ---- pooling + classifier ----
    pool_fin_kernel<<<32, 256, 0, stream>>>(pooled, pcnt, emb, emb_out);
    classifier_kernel<<<1, 256, 0, stream>>>(
        emb, Wc0, bc0, gc0, bec0, Wc1, bc1, gc1, bec1, Wc2, bc2, logits_out);
}

// Round 5
// 659.304 us; speedup vs baseline: 3.4939x; 1.1738x over previous
//
#include <hip/hip_runtime.h>
#include <hip/hip_bf16.h>
#include <math.h>

#define N_NODES 50000
#define N_EDGES 800000
#define D_IN    128
#define H1_     256
#define H2_     128
#define NG      64
#define NC_     2
#define BN_EPS  1e-5f

typedef __attribute__((ext_vector_type(8))) short bf16x8;
typedef __attribute__((ext_vector_type(4))) float f32x4;

__device__ __forceinline__ float bf2f(unsigned short u) {
    unsigned int v = ((unsigned int)u) << 16;
    return __uint_as_float(v);
}
__device__ __forceinline__ unsigned short f2bf(float f) {
    __hip_bfloat16 h = __float2bfloat16(f);
    return *reinterpret_cast<unsigned short*>(&h);
}

// ---------------------------------------------------------------------------
// CSR build
// ---------------------------------------------------------------------------
__global__ void degree_kernel(const int* __restrict__ ei, int* __restrict__ deg)
{
    int e = blockIdx.x * 256 + threadIdx.x;
    if (e < N_EDGES) atomicAdd(&deg[ei[N_EDGES + e]], 1);
}

__global__ __launch_bounds__(1024) void scan_kernel(const int* __restrict__ deg,
                                                    int* __restrict__ rowptr,
                                                    int* __restrict__ cursor)
{
    __shared__ int buf[1024];
    __shared__ int carry_s;
    if (threadIdx.x == 0) carry_s = 0;
    __syncthreads();
    for (int base = 0; base < N_NODES; base += 1024) {
        int i = base + threadIdx.x;
        int v = (i < N_NODES) ? deg[i] : 0;
        buf[threadIdx.x] = v;
        __syncthreads();
        for (int off = 1; off < 1024; off <<= 1) {
            int t = (threadIdx.x >= off) ? buf[threadIdx.x - off] : 0;
            __syncthreads();
            buf[threadIdx.x] += t;
            __syncthreads();
        }
        int carry = carry_s;
        int excl = carry + buf[threadIdx.x] - v;
        if (i < N_NODES) { rowptr[i] = excl; cursor[i] = excl; }
        if (i == N_NODES - 1) rowptr[N_NODES] = excl + v;
        __syncthreads();
        if (threadIdx.x == 1023) carry_s = carry + buf[1023];
        __syncthreads();
    }
}

__global__ void fill_kernel(const int* __restrict__ ei, int* __restrict__ cursor,
                            int* __restrict__ csr_src)
{
    int e = blockIdx.x * 256 + threadIdx.x;
    if (e < N_EDGES) {
        int d = ei[N_EDGES + e];
        int pos = atomicAdd(&cursor[d], 1);
        csr_src[pos] = ei[e];
    }
}

// ---------------------------------------------------------------------------
// f32 -> bf16 convert (4 elems/thread)
// ---------------------------------------------------------------------------
__global__ void conv_bf16_kernel(const float* __restrict__ in,
                                 unsigned short* __restrict__ out, int n4)
{
    int i = blockIdx.x * 256 + threadIdx.x;
    if (i < n4) {
        float4 v = ((const float4*)in)[i];
        ushort4 o;
        o.x = f2bf(v.x); o.y = f2bf(v.y); o.z = f2bf(v.z); o.w = f2bf(v.w);
        ((ushort4*)out)[i] = o;
    }
}

// ---------------------------------------------------------------------------
// weight swizzle into MFMA B-fragment order, f32 -> bf16.
// ---------------------------------------------------------------------------
template<int K1, int K2, int HOUT>
__global__ void wswz_kernel(const float* __restrict__ Wl, const float* __restrict__ Wr,
                            const float* __restrict__ Wp,
                            unsigned short* __restrict__ wt, unsigned short* __restrict__ wrp)
{
    constexpr int NKT_T = (K1 + K2) / 32;
    constexpr int NKT_R = K2 / 32;
    constexpr int NNT = HOUT / 16;
    const int total_t = NNT * NKT_T * 64;
    const int total_r = NNT * NKT_R * 64;
    int idx = blockIdx.x * 256 + threadIdx.x;
    if (idx < total_t) {
        int lane = idx & 63, f = idx >> 6;
        int kt = f % NKT_T, nt = f / NKT_T;
        int col = nt * 16 + (lane & 15);
        int k0 = kt * 32 + (lane >> 4) * 8;
        ushort4 lo, hi;
        unsigned short o[8];
        #pragma unroll
        for (int j = 0; j < 8; ++j) {
            int k = k0 + j;
            float v = (k < K1) ? Wl[(size_t)k * HOUT + col]
                               : Wr[(size_t)(k - K1) * HOUT + col];
            o[j] = f2bf(v);
        }
        lo.x = o[0]; lo.y = o[1]; lo.z = o[2]; lo.w = o[3];
        hi.x = o[4]; hi.y = o[5]; hi.z = o[6]; hi.w = o[7];
        ((ushort4*)wt)[idx * 2]     = lo;
        ((ushort4*)wt)[idx * 2 + 1] = hi;
    } else if (idx < total_t + total_r) {
        int i2 = idx - total_t;
        int lane = i2 & 63, f = i2 >> 6;
        int kt = f % NKT_R, nt = f / NKT_R;
        int col = nt * 16 + (lane & 15);
        int k0 = kt * 32 + (lane >> 4) * 8;
        ushort4 lo, hi;
        unsigned short o[8];
        #pragma unroll
        for (int j = 0; j < 8; ++j)
            o[j] = f2bf(Wp[(size_t)(k0 + j) * HOUT + col]);
        lo.x = o[0]; lo.y = o[1]; lo.z = o[2]; lo.w = o[3];
        hi.x = o[4]; hi.y = o[5]; hi.z = o[6]; hi.w = o[7];
        ((ushort4*)wrp)[i2 * 2]     = lo;
        ((ushort4*)wrp)[i2 * 2 + 1] = hi;
    }
}

// ---------------------------------------------------------------------------
// gather-mean from bf16 features, f32 accumulate, bf16 mean out
// ---------------------------------------------------------------------------
template<int D>
__global__ __launch_bounds__(256) void gather_mean_bf16_kernel(
    const unsigned short* __restrict__ xb, const int* __restrict__ rowptr,
    const int* __restrict__ csr_src, unsigned short* __restrict__ mean)
{
    constexpr int GT = D / 4;         // lanes per node, 4 bf16 (8B) per lane
    constexpr int NGRP = 256 / GT;
    int grp = threadIdx.x / GT;
    int t   = threadIdx.x % GT;
    int n = blockIdx.x * NGRP + grp;
    if (n >= N_NODES) return;
    int e0 = rowptr[n], e1 = rowptr[n + 1];
    const ushort4* xv = (const ushort4*)xb;
    float a0 = 0.f, a1 = 0.f, a2 = 0.f, a3 = 0.f;
    int e = e0;
    for (; e + 1 < e1; e += 2) {
        int s0 = csr_src[e], s1 = csr_src[e + 1];
        ushort4 v0 = xv[(size_t)s0 * GT + t];
        ushort4 v1 = xv[(size_t)s1 * GT + t];
        a0 += bf2f(v0.x) + bf2f(v1.x);
        a1 += bf2f(v0.y) + bf2f(v1.y);
        a2 += bf2f(v0.z) + bf2f(v1.z);
        a3 += bf2f(v0.w) + bf2f(v1.w);
    }
    if (e < e1) {
        int s0 = csr_src[e];
        ushort4 v0 = xv[(size_t)s0 * GT + t];
        a0 += bf2f(v0.x); a1 += bf2f(v0.y); a2 += bf2f(v0.z); a3 += bf2f(v0.w);
    }
    float inv = 1.0f / fmaxf((float)(e1 - e0), 1.0f);
    ushort4 o;
    o.x = f2bf(a0 * inv); o.y = f2bf(a1 * inv);
    o.z = f2bf(a2 * inv); o.w = f2bf(a3 * inv);
    ((ushort4*)mean)[(size_t)n * GT + t] = o;
}

// ---------------------------------------------------------------------------
// MFMA GEMM, fused epilogue (see round-3 notes; C/D: col=lane&15,
// row=(lane>>4)*4+reg per m89)
// ---------------------------------------------------------------------------
template<int K1, int K2, int HOUT, bool R_BF16>
__global__ __launch_bounds__(256) void gemm_mfma_kernel(
    const unsigned short* __restrict__ meanb,   // [N][K1] bf16
    const unsigned short* __restrict__ selfb,   // [N][K2] bf16
    const unsigned short* __restrict__ wt,      // swizzled [Wl;Wr]
    const unsigned short* __restrict__ wrp,     // swizzled Wp
    const float* __restrict__ bl, const float* __restrict__ bp,
    float* __restrict__ tout,
    void* __restrict__ rout,
    float* __restrict__ colsum, float* __restrict__ colsumsq)
{
    constexpr int NKT_T = (K1 + K2) / 32;
    constexpr int NKT_R = K2 / 32;
    constexpr int NKT_M = K1 / 32;
    constexpr int NNT   = HOUT / 16;
    __shared__ float sred_s[4][HOUT];
    __shared__ float sred_q[4][HOUT];

    int tid = threadIdx.x;
    int w = tid >> 6, lane = tid & 63;
    int lm = lane & 15, kq = lane >> 4;
    int arow = blockIdx.x * 64 + w * 16 + lm;
    int lrow = (arow < N_NODES) ? arow : (N_NODES - 1);

    bf16x8 af[NKT_T];
    {
        const unsigned short* mrow = meanb + (size_t)lrow * K1 + kq * 8;
        const unsigned short* srow = selfb + (size_t)lrow * K2 + kq * 8;
        #pragma unroll
        for (int kt = 0; kt < NKT_M; ++kt)
            af[kt] = *(const bf16x8*)(mrow + kt * 32);
        #pragma unroll
        for (int kt = 0; kt < NKT_R; ++kt)
            af[NKT_M + kt] = *(const bf16x8*)(srow + kt * 32);
    }

    int orow0 = blockIdx.x * 64 + w * 16 + kq * 4;
    f32x4 tv[NNT];
    float ssq[4] = {0.f, 0.f, 0.f, 0.f};

    #pragma unroll
    for (int nt = 0; nt < NNT; ++nt) {
        f32x4 acc = {0.f, 0.f, 0.f, 0.f};
        #pragma unroll
        for (int kt = 0; kt < NKT_T; ++kt) {
            bf16x8 bw = *(const bf16x8*)(wt + ((size_t)(nt * NKT_T + kt) * 64 + lane) * 8);
            acc = __builtin_amdgcn_mfma_f32_16x16x32_bf16(af[kt], bw, acc, 0, 0, 0);
        }
        float blj = bl[nt * 16 + lm];
        #pragma unroll
        for (int r = 0; r < 4; ++r) {
            acc[r] += blj;
            ssq[r] += acc[r] * acc[r];
        }
        tv[nt] = acc;

        f32x4 racc = {0.f, 0.f, 0.f, 0.f};
        #pragma unroll
        for (int kt = 0; kt < NKT_R; ++kt) {
            bf16x8 bw = *(const bf16x8*)(wrp + ((size_t)(nt * NKT_R + kt) * 64 + lane) * 8);
            racc = __builtin_amdgcn_mfma_f32_16x16x32_bf16(af[NKT_M + kt], bw, racc, 0, 0, 0);
        }
        float bpj = bp[nt * 16 + lm];
        #pragma unroll
        for (int r = 0; r < 4; ++r) {
            int orow = orow0 + r;
            if (orow < N_NODES) {
                float v = racc[r] + bpj;
                if (R_BF16)
                    ((unsigned short*)rout)[(size_t)orow * HOUT + nt * 16 + lm] = f2bf(v);
                else
                    ((float*)rout)[(size_t)orow * HOUT + nt * 16 + lm] = v;
            }
        }
    }

    #pragma unroll
    for (int off = 1; off <= 8; off <<= 1)
        #pragma unroll
        for (int r = 0; r < 4; ++r)
            ssq[r] += __shfl_xor(ssq[r], off);
    float inv[4];
    #pragma unroll
    for (int r = 0; r < 4; ++r)
        inv[r] = 1.0f / fmaxf(sqrtf(ssq[r]), 1e-12f);

    #pragma unroll
    for (int nt = 0; nt < NNT; ++nt) {
        float cs = 0.f, cq = 0.f;
        #pragma unroll
        for (int r = 0; r < 4; ++r) {
            int orow = orow0 + r;
            float v = tv[nt][r] * inv[r];
            if (orow < N_NODES) {
                tout[(size_t)orow * HOUT + nt * 16 + lm] = v;
                cs += v; cq += v * v;
            }
        }
        cs += __shfl_xor(cs, 16); cs += __shfl_xor(cs, 32);
        cq += __shfl_xor(cq, 16); cq += __shfl_xor(cq, 32);
        if (kq == 0) {
            sred_s[w][nt * 16 + lm] = cs;
            sred_q[w][nt * 16 + lm] = cq;
        }
    }
    __syncthreads();
    if (tid < HOUT) {
        float s = sred_s[0][tid] + sred_s[1][tid] + sred_s[2][tid] + sred_s[3][tid];
        float q = sred_q[0][tid] + sred_q[1][tid] + sred_q[2][tid] + sred_q[3][tid];
        atomicAdd(&colsum[tid], s);
        atomicAdd(&colsumsq[tid], q);
    }
}

// ---------------------------------------------------------------------------
template<int H>
__global__ void bn_finalize(const float* __restrict__ colsum, const float* __restrict__ colsumsq,
                            const float* __restrict__ g, const float* __restrict__ be,
                            float* __restrict__ scale, float* __restrict__ shift)
{
    int j = threadIdx.x;
    if (j < H) {
        float mu = colsum[j] / (float)N_NODES;
        float var = colsumsq[j] / (float)N_NODES - mu * mu;
        float sc = g[j] * rsqrtf(var + BN_EPS);
        scale[j] = sc;
        shift[j] = be[j] - mu * sc;
    }
}

// ---------------------------------------------------------------------------
// layer 0 epilogue: h0b = bf16( relu(t*scale+shift) + r0b )
// ---------------------------------------------------------------------------
__global__ void ew0_kernel(const float4* __restrict__ t, const ushort4* __restrict__ rb,
                           const float* __restrict__ scale, const float* __restrict__ shift,
                           ushort4* __restrict__ h0b)
{
    int gid = blockIdx.x * 256 + threadIdx.x;
    if (gid >= N_NODES * H1_ / 4) return;
    int j4 = gid & (H1_ / 4 - 1);
    float4 sc = *(const float4*)(scale + j4 * 4);
    float4 sh = *(const float4*)(shift + j4 * 4);
    float4 tv = t[gid];
    ushort4 rv = rb[gid];
    ushort4 hb;
    hb.x = f2bf(fmaxf(tv.x * sc.x + sh.x, 0.f) + bf2f(rv.x));
    hb.y = f2bf(fmaxf(tv.y * sc.y + sh.y, 0.f) + bf2f(rv.y));
    hb.z = f2bf(fmaxf(tv.z * sc.z + sh.z, 0.f) + bf2f(rv.z));
    hb.w = f2bf(fmaxf(tv.w * sc.w + sh.w, 0.f) + bf2f(rv.w));
    h0b[gid] = hb;
}

// ---------------------------------------------------------------------------
// layer 1 epilogue fused with mean-pool scatter (batch sorted -> run-length)
// ---------------------------------------------------------------------------
__global__ __launch_bounds__(H2_) void ew1_pool_kernel(
    const float* __restrict__ t, const float* __restrict__ r,
    const float* __restrict__ scale, const float* __restrict__ shift,
    const int* __restrict__ batch,
    float* __restrict__ pooled, float* __restrict__ pcnt)
{
    int j = threadIdx.x;
    int n0 = blockIdx.x * 64;
    int nend = min(n0 + 64, N_NODES);
    float acc = 0.f, cacc = 0.f;
    int run = -1;
    float sc = scale[j], sh = shift[j];
    for (int n = n0; n < nend; ++n) {
        int b = batch[n];
        if (b != run) {
            if (run >= 0) {
                atomicAdd(&pooled[run * H2_ + j], acc);
                if (j == 0) atomicAdd(&pcnt[run], cacc);
            }
            run = b; acc = 0.f; cacc = 0.f;
        }
        float v = t[(size_t)n * H2_ + j] * sc + sh;
        v = fmaxf(v, 0.f) + r[(size_t)n * H2_ + j];
        acc += v;
        cacc += 1.f;
    }
    if (run >= 0) {
        atomicAdd(&pooled[run * H2_ + j], acc);
        if (j == 0) atomicAdd(&pcnt[run], cacc);
    }
}

// ---------------------------------------------------------------------------
__global__ void pool_fin_kernel(const float* __restrict__ pooled, const float* __restrict__ pcnt,
                                float* __restrict__ emb, float* __restrict__ emb_out)
{
    int gid = blockIdx.x * blockDim.x + threadIdx.x;
    if (gid < NG * H2_) {
        int g = gid >> 7;
        float v = pooled[gid] / fmaxf(pcnt[g], 1.0f);
        emb[gid] = v;
        emb_out[gid] = v;
    }
}

// ---------------------------------------------------------------------------
// classifier MLP, single block, 1024 threads (16 waves for latency hiding).
// Stage A: 4 row-groups x 256 cols, acc[16]; Stage B: 8 x 128, acc[8].
// BN stats cross-group reduced in LDS.
// ---------------------------------------------------------------------------
__global__ __launch_bounds__(1024) void classifier_kernel(
    const float* __restrict__ emb,
    const float* __restrict__ Wc0, const float* __restrict__ bc0,
    const float* __restrict__ gc0, const float* __restrict__ bec0,
    const float* __restrict__ Wc1, const float* __restrict__ bc1,
    const float* __restrict__ gc1, const float* __restrict__ bec1,
    const float* __restrict__ Wc2, const float* __restrict__ bc2,
    float* __restrict__ logits)
{
    __shared__ float es[NG][H2_];     // 32 KB: emb, later z1
    __shared__ float z0s[NG][256];    // 64 KB
    __shared__ float red_s[1024];     // 4 KB
    __shared__ float red_q[1024];     // 4 KB
    __shared__ float scs[256], shs[256];
    int tid = threadIdx.x;
    for (int i = tid; i < NG * H2_; i += 1024) es[i >> 7][i & 127] = emb[i];
    __syncthreads();

    { // stage A: z0 = relu(bn(emb @ Wc0 + bc0))  [64x128 @ 128x256]
        int j = tid & 255, rg = tid >> 8;          // 4 groups x 16 rows
        float acc[16];
        float b = bc0[j];
        #pragma unroll
        for (int r = 0; r < 16; ++r) acc[r] = b;
        #pragma unroll 4
        for (int k = 0; k < H2_; ++k) {
            float w = Wc0[k * 256 + j];
            #pragma unroll
            for (int r = 0; r < 16; ++r) acc[r] += es[rg * 16 + r][k] * w;
        }
        float cs = 0.f, cq = 0.f;
        #pragma unroll
        for (int r = 0; r < 16; ++r) { cs += acc[r]; cq += acc[r] * acc[r]; }
        red_s[rg * 256 + j] = cs;
        red_q[rg * 256 + j] = cq;
        __syncthreads();
        if (tid < 256) {
            float s = red_s[tid] + red_s[256 + tid] + red_s[512 + tid] + red_s[768 + tid];
            float q = red_q[tid] + red_q[256 + tid] + red_q[512 + tid] + red_q[768 + tid];
            float mu = s * (1.0f / NG);
            float var = q * (1.0f / NG) - mu * mu;
            float sc = gc0[tid] * rsqrtf(var + BN_EPS);
            scs[tid] = sc;
            shs[tid] = bec0[tid] - mu * sc;
        }
        __syncthreads();
        float sc = scs[j], sh = shs[j];
        #pragma unroll
        for (int r = 0; r < 16; ++r)
            z0s[rg * 16 + r][j] = fmaxf(acc[r] * sc + sh, 0.f);
    }
    __syncthreads();

    { // stage B: z1 = relu(bn(z0 @ Wc1 + bc1))  [64x256 @ 256x128] -> es
        int j = tid & 127, rg = tid >> 7;          // 8 groups x 8 rows
        float acc[8];
        float b = bc1[j];
        #pragma unroll
        for (int r = 0; r < 8; ++r) acc[r] = b;
        #pragma unroll 4
        for (int k = 0; k < 256; ++k) {
            float w = Wc1[k * H2_ + j];
            #pragma unroll
            for (int r = 0; r < 8; ++r) acc[r] += z0s[rg * 8 + r][k] * w;
        }
        float cs = 0.f, cq = 0.f;
        #pragma unroll
        for (int r = 0; r < 8; ++r) { cs += acc[r]; cq += acc[r] * acc[r]; }
        red_s[rg * 128 + j] = cs;
        red_q[rg * 128 + j] = cq;
        __syncthreads();
        if (tid < 128) {
            float s = 0.f, q = 0.f;
            #pragma unroll
            for (int g = 0; g < 8; ++g) { s += red_s[g * 128 + tid]; q += red_q[g * 128 + tid]; }
            float mu = s * (1.0f / NG);
            float var = q * (1.0f / NG) - mu * mu;
            float sc = gc1[tid] * rsqrtf(var + BN_EPS);
            scs[tid] = sc;
            shs[tid] = bec1[tid] - mu * sc;
        }
        __syncthreads();
        float sc = scs[j], sh = shs[j];
        #pragma unroll
        for (int r = 0; r < 8; ++r)
            es[rg * 8 + r][j] = fmaxf(acc[r] * sc + sh, 0.f);
    }
    __syncthreads();

    if (tid < NG * NC_) { // stage C: logits = z1 @ Wc2 + bc2
        int r2 = tid >> 1, c = tid & 1;
        float acc = bc2[c];
        #pragma unroll 4
        for (int k = 0; k < H2_; ++k) acc += es[r2][k] * Wc2[k * NC_ + c];
        logits[r2 * NC_ + c] = acc;
    }
}

// ---------------------------------------------------------------------------
extern "C" void kernel_launch(void* const* d_in, const int* in_sizes, int n_in,
                              void* d_out, int out_size, void* d_ws, size_t ws_size,
                              hipStream_t stream)
{
    const float* x    = (const float*)d_in[0];
    const int*   ei   = (const int*)d_in[1];
    const int*   batch= (const int*)d_in[2];
    const float* Wl0  = (const float*)d_in[3];
    const float* bl0  = (const float*)d_in[4];
    const float* Wr0  = (const float*)d_in[5];
    const float* g0   = (const float*)d_in[6];
    const float* be0  = (const float*)d_in[7];
    const float* Wl1  = (const float*)d_in[8];
    const float* bl1  = (const float*)d_in[9];
    const float* Wr1  = (const float*)d_in[10];
    const float* g1   = (const float*)d_in[11];
    const float* be1  = (const float*)d_in[12];
    const float* Wp0  = (const float*)d_in[13];
    const float* bp0  = (const float*)d_in[14];
    const float* Wp1  = (const float*)d_in[15];
    const float* bp1  = (const float*)d_in[16];
    const float* Wc0  = (const float*)d_in[17];
    const float* bc0  = (const float*)d_in[18];
    const float* gc0  = (const float*)d_in[19];
    const float* bec0 = (const float*)d_in[20];
    const float* Wc1  = (const float*)d_in[21];
    const float* bc1  = (const float*)d_in[22];
    const float* gc1  = (const float*)d_in[23];
    const float* bec1 = (const float*)d_in[24];
    const float* Wc2  = (const float*)d_in[25];
    const float* bc2  = (const float*)d_in[26];

    // ---- workspace layout (float units). Total = 33,131,072 fl = 126.4 MiB
    float* ws = (float*)d_ws;
    float* fs = ws;                              // 32768 small area
    float* colsum0   = fs;                       // 256
    float* colsumsq0 = fs + 256;                 // 256
    float* colsum1   = fs + 512;                 // 128
    float* colsumsq1 = fs + 640;                 // 128
    float* ss0       = fs + 768;                 // 512 (scale0, shift0)
    float* ss1       = fs + 1280;                // 256 (scale1, shift1)
    float* pooled    = fs + 1536;                // 8192
    float* pcnt      = fs + 9728;                // 64
    float* emb       = fs + 9792;                // 8192

    unsigned short* wsz0t = (unsigned short*)(ws + 32768);   // 65536 bf16
    unsigned short* wsz0r = (unsigned short*)(ws + 65536);   // 32768 bf16
    unsigned short* wsz1t = (unsigned short*)(ws + 81920);   // 65536 bf16
    unsigned short* wsz1r = (unsigned short*)(ws + 114688);  // 32768 bf16

    int* deg    = (int*)(ws + 131072);           // 50000
    int* rowptr = deg + 50000;                   // 50001
    int* cursor = rowptr + 50001;                // 50000
    int* csr    = cursor + 50000;                // 800000

    unsigned short* h0b    = (unsigned short*)(ws + 1131072);   // 12.8M bf16
    unsigned short* xb     = (unsigned short*)(ws + 7531072);   // 6.4M bf16
    unsigned short* meanb0 = (unsigned short*)(ws + 10731072);  // 6.4M bf16
    unsigned short* meanb1 = xb;                                // reuse
    float* t0  = ws + 13931072;                  // 12.8M f32
    float* t1  = t0;                             // 6.4M f32 (reuse)
    float* r1  = t0 + 6400000;                   // 6.4M f32 (reuse)
    unsigned short* r0b = (unsigned short*)(ws + 26731072);     // 12.8M bf16

    float* logits_out = (float*)d_out;
    float* emb_out    = logits_out + NG * NC_;

    hipMemsetAsync(fs, 0, 32768 * sizeof(float), stream);
    hipMemsetAsync(deg, 0, 50000 * sizeof(int), stream);

    // ---- prep: CSR, bf16 x, swizzled weights ----
    degree_kernel<<<(N_EDGES + 255) / 256, 256, 0, stream>>>(ei, deg);
    scan_kernel<<<1, 1024, 0, stream>>>(deg, rowptr, cursor);
    fill_kernel<<<(N_EDGES + 255) / 256, 256, 0, stream>>>(ei, cursor, csr);
    conv_bf16_kernel<<<(N_NODES * D_IN / 4 + 255) / 256, 256, 0, stream>>>(
        x, xb, N_NODES * D_IN / 4);
    wswz_kernel<D_IN, D_IN, H1_><<<48, 256, 0, stream>>>(Wl0, Wr0, Wp0, wsz0t, wsz0r);
    wswz_kernel<H1_, H1_, H2_><<<48, 256, 0, stream>>>(Wl1, Wr1, Wp1, wsz1t, wsz1r);

    // ---- layer 0 ----
    gather_mean_bf16_kernel<D_IN><<<(N_NODES + 7) / 8, 256, 0, stream>>>(
        xb, rowptr, csr, meanb0);
    gemm_mfma_kernel<D_IN, D_IN, H1_, true><<<(N_NODES + 63) / 64, 256, 0, stream>>>(
        meanb0, xb, wsz0t, wsz0r, bl0, bp0, t0, r0b, colsum0, colsumsq0);
    bn_finalize<H1_><<<1, H1_, 0, stream>>>(colsum0, colsumsq0, g0, be0, ss0, ss0 + 256);
    ew0_kernel<<<(N_NODES * H1_ / 4 + 255) / 256, 256, 0, stream>>>(
        (const float4*)t0, (const ushort4*)r0b, ss0, ss0 + 256, (ushort4*)h0b);

    // ---- layer 1 ----
    gather_mean_bf16_kernel<H1_><<<(N_NODES + 3) / 4, 256, 0, stream>>>(
        h0b, rowptr, csr, meanb1);
    gemm_mfma_kernel<H1_, H1_, H2_, false><<<(N_NODES + 63) / 64, 256, 0, stream>>>(
        meanb1, h0b, wsz1t, wsz1r, bl1, bp1, t1, r1, colsum1, colsumsq1);
    bn_finalize<H2_><<<1, H2_, 0, stream>>>(colsum1, colsumsq1, g1, be1, ss1, ss1 + 128);
    ew1_pool_kernel<<<(N_NODES + 63) / 64, H2_, 0, stream>>>(
        t1, r1, ss1, ss1 + 128, batch, pooled, pcnt);

    // ---- pooling + classifier ----
    pool_fin_kernel<<<32, 256, 0, stream>>>(pooled, pcnt, emb, emb_out);
    classifier_kernel<<<1, 1024, 0, stream>>>(
        emb, Wc0, bc0, gc0, bec0, Wc1, bc1, gc1, bec1, Wc2, bc2, logits_out);
}